// Round 1
// baseline (1789.566 us; speedup 1.0000x reference)
//
#include <hip/hip_runtime.h>
#include <cstdint>
#include <cstddef>

// ---------------------------------------------------------------------------
// GAT 4-layer network, fused per-layer:
//   GEMM (h = in @ W) -> alpha dots -> CSR-based segment-softmax aggregation
// CSR built per launch (no static state): deg histogram -> scan -> scatter.
// ---------------------------------------------------------------------------

__device__ __forceinline__ float leaky(float e) { return e < 0.f ? 0.2f * e : e; }

// ---------------- CSR build ----------------

__global__ __launch_bounds__(256) void k_deg(const int* __restrict__ ei, int ER, int ET,
                                             int* __restrict__ deg) {
  int e = blockIdx.x * 256 + threadIdx.x;
  if (e >= ET) return;
  int d = (e < ER) ? ei[ER + e] : (e - ER);   // ei rows: [0..ER)=src, [ER..2ER)=dst
  atomicAdd(&deg[d], 1);
}

__global__ __launch_bounds__(256) void k_scan1(const int* __restrict__ deg, int* __restrict__ rp,
                                               int* __restrict__ bsums, int n) {
  __shared__ int sh[256];
  int tid = threadIdx.x;
  int base = blockIdx.x * 2048 + tid * 8;
  int pre[8];
  int s = 0;
#pragma unroll
  for (int j = 0; j < 8; ++j) {
    int idx = base + j;
    int v = (idx < n) ? deg[idx] : 0;
    pre[j] = s;
    s += v;
  }
  sh[tid] = s;
  __syncthreads();
  for (int d = 1; d < 256; d <<= 1) {
    int t = (tid >= d) ? sh[tid - d] : 0;
    __syncthreads();
    if (tid >= d) sh[tid] += t;
    __syncthreads();
  }
  int excl = sh[tid] - s;
#pragma unroll
  for (int j = 0; j < 8; ++j) {
    int idx = base + j;
    if (idx < n) rp[idx] = excl + pre[j];
  }
  if (tid == 255) bsums[blockIdx.x] = sh[255];
}

__global__ void k_scan2(int* bsums, int nb) {
  for (int i = 1; i < nb; ++i) bsums[i] += bsums[i - 1];  // 49 iters, trivial
}

__global__ __launch_bounds__(256) void k_scan3(int* __restrict__ rp, const int* __restrict__ bsums,
                                               int n, int ET) {
  int i = blockIdx.x * 256 + threadIdx.x;
  if (i > n) return;
  if (i == n) { rp[n] = ET; return; }
  int b = i >> 11;
  if (b > 0) rp[i] += bsums[b - 1];
}

__global__ __launch_bounds__(256) void k_scatter(const int* __restrict__ ei, int ER, int ET,
                                                 const int* __restrict__ rp, int* __restrict__ fill,
                                                 int* __restrict__ col) {
  int e = blockIdx.x * 256 + threadIdx.x;
  if (e >= ET) return;
  int s, d;
  if (e < ER) { s = ei[e]; d = ei[ER + e]; } else { s = e - ER; d = s; }
  int pos = rp[d] + atomicAdd(&fill[d], 1);
  col[pos] = s;
}

// ---------------- GEMM: out[N, COLS] = X[N,128] @ W[128, COLS] ----------------
// Block: 256 threads, 64 rows x COLS. Thread (ty,tx): 4 rows x TN cols.

template <int COLS>
__global__ __launch_bounds__(256) void k_gemm(const float* __restrict__ X,
                                              const float* __restrict__ W,
                                              float* __restrict__ out, int N) {
  constexpr int KC = 32, FIN = 128;
  constexpr int TN = COLS / 16;
  __shared__ float sX[KC][68];          // transposed x chunk, padded
  __shared__ float sW[KC][COLS + 4];    // w chunk, padded
  int tid = threadIdx.x;
  int ty = tid >> 4, tx = tid & 15;
  int row0 = blockIdx.x * 64;

  float acc[4][TN];
#pragma unroll
  for (int i = 0; i < 4; ++i)
#pragma unroll
    for (int j = 0; j < TN; ++j) acc[i][j] = 0.f;

  for (int kc = 0; kc < FIN; kc += KC) {
    // stage X chunk (64 rows x 32 k), transposed into sX[k][r]
    {
      int r = tid >> 2, kq = tid & 3;            // 256 threads -> 64 rows x 4 quads
      int grow = row0 + r; if (grow >= N) grow = N - 1;
      const float4* gp = (const float4*)(X + (size_t)grow * FIN + kc + kq * 8);
      float4 v0 = gp[0], v1 = gp[1];
      int kb = kq * 8;
      sX[kb + 0][r] = v0.x; sX[kb + 1][r] = v0.y; sX[kb + 2][r] = v0.z; sX[kb + 3][r] = v0.w;
      sX[kb + 4][r] = v1.x; sX[kb + 5][r] = v1.y; sX[kb + 6][r] = v1.z; sX[kb + 7][r] = v1.w;
    }
    // stage W chunk (32 k x COLS)
    for (int i = tid; i < KC * (COLS / 4); i += 256) {
      int k = i / (COLS / 4), c4 = i % (COLS / 4);
      float4 v = *(const float4*)(W + (size_t)(kc + k) * COLS + c4 * 4);
      *(float4*)&sW[k][c4 * 4] = v;
    }
    __syncthreads();
#pragma unroll
    for (int k = 0; k < KC; ++k) {
      float4 a4 = *(const float4*)&sX[k][ty * 4];
      float av[4] = {a4.x, a4.y, a4.z, a4.w};
      float bv[TN];
#pragma unroll
      for (int j4 = 0; j4 < TN / 4; ++j4) {
        float4 b4 = *(const float4*)&sW[k][tx * TN + j4 * 4];
        bv[j4 * 4 + 0] = b4.x; bv[j4 * 4 + 1] = b4.y; bv[j4 * 4 + 2] = b4.z; bv[j4 * 4 + 3] = b4.w;
      }
#pragma unroll
      for (int i = 0; i < 4; ++i)
#pragma unroll
        for (int j = 0; j < TN; ++j) acc[i][j] += av[i] * bv[j];
    }
    __syncthreads();
  }
#pragma unroll
  for (int i = 0; i < 4; ++i) {
    int row = row0 + ty * 4 + i;
    if (row < N) {
#pragma unroll
      for (int j4 = 0; j4 < TN / 4; ++j4) {
        float4 o;
        o.x = acc[i][j4 * 4 + 0]; o.y = acc[i][j4 * 4 + 1];
        o.z = acc[i][j4 * 4 + 2]; o.w = acc[i][j4 * 4 + 3];
        *(float4*)(out + (size_t)row * COLS + tx * TN + j4 * 4) = o;
      }
    }
  }
}

// ---------------- alpha dots: one wave per node ----------------

template <int H, int C>
__global__ __launch_bounds__(256) void k_alpha(const float* __restrict__ h,
                                               const float* __restrict__ aws,
                                               const float* __restrict__ awd,
                                               float* __restrict__ asg, float* __restrict__ adg,
                                               int N) {
  constexpr int HC = H * C;
  constexpr int VPL = HC / 64;       // values per lane (2 or 1)
  constexpr int LPH = C / VPL;       // lanes per head (16 or 64)
  int lane = threadIdx.x & 63;
  int n = blockIdx.x * (blockDim.x >> 6) + (threadIdx.x >> 6);
  if (n >= N) return;
  float ss, sd;
  if (VPL == 2) {
    float2 hv = *(const float2*)(h + (size_t)n * HC + lane * 2);
    float2 w1 = *(const float2*)(aws + lane * 2);
    float2 w2 = *(const float2*)(awd + lane * 2);
    ss = hv.x * w1.x + hv.y * w1.y;
    sd = hv.x * w2.x + hv.y * w2.y;
  } else {
    float hv = h[(size_t)n * HC + lane];
    ss = hv * aws[lane];
    sd = hv * awd[lane];
  }
#pragma unroll
  for (int m = 1; m < LPH; m <<= 1) {
    ss += __shfl_xor(ss, m);
    sd += __shfl_xor(sd, m);
  }
  if ((lane % LPH) == 0) {
    int hd = lane / LPH;
    asg[(size_t)n * H + hd] = ss;
    adg[(size_t)n * H + hd] = sd;
  }
}

// ---------------- aggregation: one wave per destination node ----------------
// Fused: edge scores, segment max, exp, denom, weighted sum, bias.

template <int H, int C>
__global__ __launch_bounds__(256) void k_agg(const int* __restrict__ rp, const int* __restrict__ col,
                                             const float* __restrict__ h,
                                             const float* __restrict__ asg,
                                             const float* __restrict__ adg,
                                             const float* __restrict__ bias,
                                             float* __restrict__ out, int N) {
  constexpr int HC = H * C;
  constexpr int VPL = HC / 64;
  int lane = threadIdx.x & 63;
  int n = blockIdx.x * (blockDim.x >> 6) + (threadIdx.x >> 6);
  if (n >= N) return;
  int head = (lane * VPL) / C;
  float adn = adg[(size_t)n * H + head];
  int s0 = rp[n], s1 = rp[n + 1];
  float m = -1e30f;
  for (int i = s0; i < s1; ++i) {
    int s = col[i];
    float e = leaky(asg[(size_t)s * H + head] + adn);
    m = fmaxf(m, e);
  }
  float denom = 0.f, a0 = 0.f, a1 = 0.f;
  for (int i = s0; i < s1; ++i) {
    int s = col[i];
    float e = leaky(asg[(size_t)s * H + head] + adn);
    float p = __expf(e - m);
    denom += p;
    if (VPL == 2) {
      float2 hv = *(const float2*)(h + (size_t)s * HC + lane * 2);
      a0 += p * hv.x;
      a1 += p * hv.y;
    } else {
      a0 += p * h[(size_t)s * HC + lane];
    }
  }
  float inv = 1.f / denom;
  if (VPL == 2) {
    float2 o;
    o.x = a0 * inv + bias[lane * 2];
    o.y = a1 * inv + bias[lane * 2 + 1];
    *(float2*)(out + (size_t)n * HC + lane * 2) = o;
  } else {
    out[(size_t)n * HC + lane] = a0 * inv + bias[lane];
  }
}

// ---------------- BatchNorm (training-mode batch stats) ----------------

__global__ __launch_bounds__(512) void k_bnstats1(const float* __restrict__ t,
                                                  float* __restrict__ p1, float* __restrict__ p2,
                                                  int N) {
  __shared__ float ls[4][128], ls2[4][128];
  int c = threadIdx.x & 127, q = threadIdx.x >> 7;
  float s = 0.f, s2 = 0.f;
  for (int r = blockIdx.x * 4 + q; r < N; r += gridDim.x * 4) {
    float v = t[(size_t)r * 128 + c];
    s += v;
    s2 += v * v;
  }
  ls[q][c] = s; ls2[q][c] = s2;
  __syncthreads();
  if (q == 0) {
    s = ls[0][c] + ls[1][c] + ls[2][c] + ls[3][c];
    s2 = ls2[0][c] + ls2[1][c] + ls2[2][c] + ls2[3][c];
    p1[blockIdx.x * 128 + c] = s;
    p2[blockIdx.x * 128 + c] = s2;
  }
}

__global__ void k_bnstats2(const float* __restrict__ p1, const float* __restrict__ p2,
                           float* __restrict__ mu, float* __restrict__ rstd, int G, int N) {
  int c = threadIdx.x;  // 128 threads
  float s = 0.f, s2 = 0.f;
  for (int b = 0; b < G; ++b) { s += p1[b * 128 + c]; s2 += p2[b * 128 + c]; }
  float m = s / (float)N;
  float var = s2 / (float)N - m * m;
  mu[c] = m;
  rstd[c] = rsqrtf(var + 1e-5f);
}

__global__ __launch_bounds__(256) void k_bnapply1(const float* __restrict__ t,
                                                  const float* __restrict__ mu,
                                                  const float* __restrict__ rstd,
                                                  const float* __restrict__ g,
                                                  const float* __restrict__ be,
                                                  float* __restrict__ o, int n4) {
  int i = blockIdx.x * 256 + threadIdx.x;
  if (i >= n4) return;
  float4 v = ((const float4*)t)[i];
  int c = (i & 31) * 4;
  float4 r;
  r.x = fmaxf((v.x - mu[c + 0]) * rstd[c + 0] * g[c + 0] + be[c + 0], 0.f);
  r.y = fmaxf((v.y - mu[c + 1]) * rstd[c + 1] * g[c + 1] + be[c + 1], 0.f);
  r.z = fmaxf((v.z - mu[c + 2]) * rstd[c + 2] * g[c + 2] + be[c + 2], 0.f);
  r.w = fmaxf((v.w - mu[c + 3]) * rstd[c + 3] * g[c + 3] + be[c + 3], 0.f);
  ((float4*)o)[i] = r;
}

// out2 = relu(bn(t) + 0.5*skip); writes t := out1 + out2 (in place; t doubles as sum buffer)
__global__ __launch_bounds__(256) void k_bnapply2(float* __restrict__ t,
                                                  const float* __restrict__ skip,
                                                  const float* __restrict__ out1,
                                                  const float* __restrict__ mu,
                                                  const float* __restrict__ rstd,
                                                  const float* __restrict__ g,
                                                  const float* __restrict__ be, int n4) {
  int i = blockIdx.x * 256 + threadIdx.x;
  if (i >= n4) return;
  float4 v = ((const float4*)t)[i];
  float4 sk = ((const float4*)skip)[i];
  float4 o1 = ((const float4*)out1)[i];
  int c = (i & 31) * 4;
  float4 r;
  r.x = o1.x + fmaxf((v.x - mu[c + 0]) * rstd[c + 0] * g[c + 0] + be[c + 0] + 0.5f * sk.x, 0.f);
  r.y = o1.y + fmaxf((v.y - mu[c + 1]) * rstd[c + 1] * g[c + 1] + be[c + 1] + 0.5f * sk.y, 0.f);
  r.z = o1.z + fmaxf((v.z - mu[c + 2]) * rstd[c + 2] * g[c + 2] + be[c + 2] + 0.5f * sk.z, 0.f);
  r.w = o1.w + fmaxf((v.w - mu[c + 3]) * rstd[c + 3] * g[c + 3] + be[c + 3] + 0.5f * sk.w, 0.f);
  ((float4*)t)[i] = r;
}

// ---------------------------------------------------------------------------

extern "C" void kernel_launch(void* const* d_in, const int* in_sizes, int n_in,
                              void* d_out, int out_size, void* d_ws, size_t ws_size,
                              hipStream_t stream) {
  const float* x = (const float*)d_in[0];
  const int* ei = (const int*)d_in[1];
  const float* W[4]  = {(const float*)d_in[2], (const float*)d_in[6],
                        (const float*)d_in[10], (const float*)d_in[14]};
  const float* AS[4] = {(const float*)d_in[3], (const float*)d_in[7],
                        (const float*)d_in[11], (const float*)d_in[15]};
  const float* AD[4] = {(const float*)d_in[4], (const float*)d_in[8],
                        (const float*)d_in[12], (const float*)d_in[16]};
  const float* B[4]  = {(const float*)d_in[5], (const float*)d_in[9],
                        (const float*)d_in[13], (const float*)d_in[17]};
  const float* g1 = (const float*)d_in[18];
  const float* be1 = (const float*)d_in[19];
  const float* g2 = (const float*)d_in[20];
  const float* be2 = (const float*)d_in[21];

  const int N = in_sizes[0] / 128;
  const int ER = in_sizes[1] / 2;
  const int ET = ER + N;

  // workspace carve-up (256B aligned)
  char* ws = (char*)d_ws;
  size_t off = 0;
  auto carve = [&](size_t bytes) {
    size_t o = off;
    off = (off + bytes + 255) & ~(size_t)255;
    return (void*)(ws + o);
  };
  int* rowptr = (int*)carve((size_t)(N + 1) * 4);
  int* fill   = (int*)carve((size_t)N * 4);
  int* col    = (int*)carve((size_t)ET * 4);
  int* bsums  = (int*)carve(64 * 4);
  float* asg  = (float*)carve((size_t)N * 4 * 4);
  float* adg  = (float*)carve((size_t)N * 4 * 4);
  float* hbuf = (float*)carve((size_t)N * 128 * 4);
  float* skipb= (float*)carve((size_t)N * 128 * 4);
  float* out1b= (float*)carve((size_t)N * 128 * 4);
  float* tmpf = (float*)carve((size_t)N * 128 * 4);   // also the out1+out2 sum buffer
  float* p1   = (float*)carve(128 * 128 * 4);
  float* p2   = (float*)carve(128 * 128 * 4);
  float* mu   = (float*)carve(128 * 4);
  float* rstd = (float*)carve(128 * 4);
  (void)ws_size;

  const int nb = (N + 2047) / 2048;
  const int gE = (ET + 255) / 256;
  const int gN4 = (N + 3) / 4;       // wave-per-node kernels (4 waves/block)
  const int gG = (N + 63) / 64;      // gemm blocks
  const int n4 = N * 32;             // float4 count of [N,128]
  const int gP = (n4 + 255) / 256;

  // ---- CSR build ----
  hipMemsetAsync(fill, 0, (size_t)N * 4, stream);
  k_deg<<<gE, 256, 0, stream>>>(ei, ER, ET, fill);
  k_scan1<<<nb, 256, 0, stream>>>(fill, rowptr, bsums, N);
  k_scan2<<<1, 1, 0, stream>>>(bsums, nb);
  k_scan3<<<(N + 256) / 256, 256, 0, stream>>>(rowptr, bsums, N, ET);
  hipMemsetAsync(fill, 0, (size_t)N * 4, stream);
  k_scatter<<<gE, 256, 0, stream>>>(ei, ER, ET, rowptr, fill, col);

  // ---- layer 0: x -> skipb ----
  k_gemm<128><<<gG, 256, 0, stream>>>(x, W[0], hbuf, N);
  k_alpha<4, 32><<<gN4, 256, 0, stream>>>(hbuf, AS[0], AD[0], asg, adg, N);
  k_agg<4, 32><<<gN4, 256, 0, stream>>>(rowptr, col, hbuf, asg, adg, B[0], skipb, N);

  // ---- layer 1: skipb -> tmpf -> bn/relu -> out1b ----
  k_gemm<128><<<gG, 256, 0, stream>>>(skipb, W[1], hbuf, N);
  k_alpha<4, 32><<<gN4, 256, 0, stream>>>(hbuf, AS[1], AD[1], asg, adg, N);
  k_agg<4, 32><<<gN4, 256, 0, stream>>>(rowptr, col, hbuf, asg, adg, B[1], tmpf, N);
  k_bnstats1<<<128, 512, 0, stream>>>(tmpf, p1, p2, N);
  k_bnstats2<<<1, 128, 0, stream>>>(p1, p2, mu, rstd, 128, N);
  k_bnapply1<<<gP, 256, 0, stream>>>(tmpf, mu, rstd, g1, be1, out1b, n4);

  // ---- layer 2: out1b -> tmpf -> bn + 0.5*skip, relu, + out1 -> tmpf ----
  k_gemm<128><<<gG, 256, 0, stream>>>(out1b, W[2], hbuf, N);
  k_alpha<4, 32><<<gN4, 256, 0, stream>>>(hbuf, AS[2], AD[2], asg, adg, N);
  k_agg<4, 32><<<gN4, 256, 0, stream>>>(rowptr, col, hbuf, asg, adg, B[2], tmpf, N);
  k_bnstats1<<<128, 512, 0, stream>>>(tmpf, p1, p2, N);
  k_bnstats2<<<1, 128, 0, stream>>>(p1, p2, mu, rstd, 128, N);
  k_bnapply2<<<gP, 256, 0, stream>>>(tmpf, skipb, out1b, mu, rstd, g2, be2, n4);

  // ---- layer 3: tmpf -> d_out (H=1, C=64) ----
  k_gemm<64><<<gG, 256, 0, stream>>>(tmpf, W[3], hbuf, N);
  k_alpha<1, 64><<<gN4, 256, 0, stream>>>(hbuf, AS[3], AD[3], asg, adg, N);
  k_agg<1, 64><<<gN4, 256, 0, stream>>>(rowptr, col, hbuf, asg, adg, B[3], (float*)d_out, N);
}

// Round 2
// 1237.407 us; speedup vs baseline: 1.4462x; 1.4462x over previous
//
#include <hip/hip_runtime.h>
#include <cstdint>
#include <cstddef>

// ---------------------------------------------------------------------------
// GAT 4-layer network.
// Per layer: fused GEMM (h = in @ W, bf16 h out + alpha_src/dst in epilogue)
//            -> CSR segment-softmax aggregation (single-pass online softmax,
//               bf16 h gather, col broadcast via shuffle).
// CSR built per launch (no static state): deg histogram -> scan -> scatter.
// ---------------------------------------------------------------------------

typedef unsigned int uint;
typedef unsigned short ushort_t;

__device__ __forceinline__ float leaky(float e) { return e < 0.f ? 0.2f * e : e; }
__device__ __forceinline__ float bflo(uint u) { return __uint_as_float(u << 16); }
__device__ __forceinline__ float bfhi(uint u) { return __uint_as_float(u & 0xffff0000u); }
__device__ __forceinline__ ushort_t f2bf(float f) {
  uint u = __float_as_uint(f);
  u += 0x7fffu + ((u >> 16) & 1u);           // round-to-nearest-even
  return (ushort_t)(u >> 16);
}
__device__ __forceinline__ float sel4(int hd, float v0, float v1, float v2, float v3) {
  float a = (hd & 1) ? v1 : v0;
  float b = (hd & 1) ? v3 : v2;
  return (hd & 2) ? b : a;
}

// ---------------- CSR build ----------------

__global__ __launch_bounds__(256) void k_deg(const int* __restrict__ ei, int ER, int ET,
                                             int* __restrict__ deg) {
  int e = blockIdx.x * 256 + threadIdx.x;
  if (e >= ET) return;
  int d = (e < ER) ? ei[ER + e] : (e - ER);
  atomicAdd(&deg[d], 1);
}

__global__ __launch_bounds__(256) void k_scan1(const int* __restrict__ deg, int* __restrict__ rp,
                                               int* __restrict__ bsums, int n) {
  __shared__ int sh[256];
  int tid = threadIdx.x;
  int base = blockIdx.x * 2048 + tid * 8;
  int pre[8];
  int s = 0;
#pragma unroll
  for (int j = 0; j < 8; ++j) {
    int idx = base + j;
    int v = (idx < n) ? deg[idx] : 0;
    pre[j] = s;
    s += v;
  }
  sh[tid] = s;
  __syncthreads();
  for (int d = 1; d < 256; d <<= 1) {
    int t = (tid >= d) ? sh[tid - d] : 0;
    __syncthreads();
    if (tid >= d) sh[tid] += t;
    __syncthreads();
  }
  int excl = sh[tid] - s;
#pragma unroll
  for (int j = 0; j < 8; ++j) {
    int idx = base + j;
    if (idx < n) rp[idx] = excl + pre[j];
  }
  if (tid == 255) bsums[blockIdx.x] = sh[255];
}

__global__ void k_scan2(int* bsums, int nb) {
  for (int i = 1; i < nb; ++i) bsums[i] += bsums[i - 1];
}

__global__ __launch_bounds__(256) void k_scan3(int* __restrict__ rp, const int* __restrict__ bsums,
                                               int n, int ET) {
  int i = blockIdx.x * 256 + threadIdx.x;
  if (i > n) return;
  if (i == n) { rp[n] = ET; return; }
  int b = i >> 11;
  if (b > 0) rp[i] += bsums[b - 1];
}

__global__ __launch_bounds__(256) void k_scatter(const int* __restrict__ ei, int ER, int ET,
                                                 const int* __restrict__ rp, int* __restrict__ fill,
                                                 int* __restrict__ col) {
  int e = blockIdx.x * 256 + threadIdx.x;
  if (e >= ET) return;
  int s, d;
  if (e < ER) { s = ei[e]; d = ei[ER + e]; } else { s = e - ER; d = s; }
  int pos = rp[d] + atomicAdd(&fill[d], 1);
  col[pos] = s;
}

// ---------------- fused GEMM: h_bf16[N,COLS] = X[N,128] @ W[128,COLS],
//                  + alpha_src/alpha_dst dots in epilogue ----------------
// Block: 256 threads, 64 rows. Thread (ty,tx): 4 rows x TN cols.

template <int COLS, int H>
__global__ __launch_bounds__(256) void k_gemm(const float* __restrict__ X,
                                              const float* __restrict__ W,
                                              const float* __restrict__ aS,
                                              const float* __restrict__ aD,
                                              ushort_t* __restrict__ hbf,
                                              float* __restrict__ asg,
                                              float* __restrict__ adg, int N) {
  constexpr int KC = 32, FIN = 128;
  constexpr int TN = COLS / 16;
  __shared__ float sX[KC][68];
  __shared__ float sW[KC][COLS + 4];
  int tid = threadIdx.x;
  int ty = tid >> 4, tx = tid & 15;
  int row0 = blockIdx.x * 64;

  float acc[4][TN];
#pragma unroll
  for (int i = 0; i < 4; ++i)
#pragma unroll
    for (int j = 0; j < TN; ++j) acc[i][j] = 0.f;

  for (int kc = 0; kc < FIN; kc += KC) {
    {
      int r = tid >> 2, kq = tid & 3;
      int grow = row0 + r; if (grow >= N) grow = N - 1;
      const float4* gp = (const float4*)(X + (size_t)grow * FIN + kc + kq * 8);
      float4 v0 = gp[0], v1 = gp[1];
      int kb = kq * 8;
      sX[kb + 0][r] = v0.x; sX[kb + 1][r] = v0.y; sX[kb + 2][r] = v0.z; sX[kb + 3][r] = v0.w;
      sX[kb + 4][r] = v1.x; sX[kb + 5][r] = v1.y; sX[kb + 6][r] = v1.z; sX[kb + 7][r] = v1.w;
    }
    for (int i = tid; i < KC * (COLS / 4); i += 256) {
      int k = i / (COLS / 4), c4 = i % (COLS / 4);
      float4 v = *(const float4*)(W + (size_t)(kc + k) * COLS + c4 * 4);
      *(float4*)&sW[k][c4 * 4] = v;
    }
    __syncthreads();
#pragma unroll
    for (int k = 0; k < KC; ++k) {
      float4 a4 = *(const float4*)&sX[k][ty * 4];
      float av[4] = {a4.x, a4.y, a4.z, a4.w};
      float bv[TN];
#pragma unroll
      for (int j4 = 0; j4 < TN / 4; ++j4) {
        float4 b4 = *(const float4*)&sW[k][tx * TN + j4 * 4];
        bv[j4 * 4 + 0] = b4.x; bv[j4 * 4 + 1] = b4.y; bv[j4 * 4 + 2] = b4.z; bv[j4 * 4 + 3] = b4.w;
      }
#pragma unroll
      for (int i = 0; i < 4; ++i)
#pragma unroll
        for (int j = 0; j < TN; ++j) acc[i][j] += av[i] * bv[j];
    }
    __syncthreads();
  }

  // epilogue: alpha dots (fp32 from fp32 acc) + bf16 h store
#pragma unroll
  for (int i = 0; i < 4; ++i) {
    int row = row0 + ty * 4 + i;
    float ps = 0.f, pd = 0.f;
#pragma unroll
    for (int j = 0; j < TN; ++j) {
      float as_ = aS[tx * TN + j];
      float ad_ = aD[tx * TN + j];
      ps += acc[i][j] * as_;
      pd += acc[i][j] * ad_;
    }
    if (COLS == 128) {
      // head = tx>>2 (8 cols per thread, 32 per head); reduce over tx&3
      ps += __shfl_xor(ps, 1); ps += __shfl_xor(ps, 2);
      pd += __shfl_xor(pd, 1); pd += __shfl_xor(pd, 2);
      if (row < N && (tx & 3) == 0) {
        asg[(size_t)row * 4 + (tx >> 2)] = ps;
        adg[(size_t)row * 4 + (tx >> 2)] = pd;
      }
    } else {
      ps += __shfl_xor(ps, 1); ps += __shfl_xor(ps, 2);
      ps += __shfl_xor(ps, 4); ps += __shfl_xor(ps, 8);
      pd += __shfl_xor(pd, 1); pd += __shfl_xor(pd, 2);
      pd += __shfl_xor(pd, 4); pd += __shfl_xor(pd, 8);
      if (row < N && tx == 0) { asg[row] = ps; adg[row] = pd; }
    }
    if (row < N) {
      if (COLS == 128) {
        uint w0 = (uint)f2bf(acc[i][0]) | ((uint)f2bf(acc[i][1]) << 16);
        uint w1 = (uint)f2bf(acc[i][2]) | ((uint)f2bf(acc[i][3]) << 16);
        uint w2 = (uint)f2bf(acc[i][4]) | ((uint)f2bf(acc[i][5]) << 16);
        uint w3 = (uint)f2bf(acc[i][6]) | ((uint)f2bf(acc[i][7]) << 16);
        uint4 o = make_uint4(w0, w1, w2, w3);
        *(uint4*)(hbf + (size_t)row * COLS + tx * 8) = o;
      } else {
        uint w0 = (uint)f2bf(acc[i][0]) | ((uint)f2bf(acc[i][1]) << 16);
        uint w1 = (uint)f2bf(acc[i][2]) | ((uint)f2bf(acc[i][3]) << 16);
        uint2 o = make_uint2(w0, w1);
        *(uint2*)(hbf + (size_t)row * COLS + tx * 4) = o;
      }
    }
  }
}

// ---------------- aggregation: one wave per destination node ----------------
// Single-pass online softmax. cols vector-loaded once per 64 edges and
// broadcast by shuffle; per-edge p computed lane-parallel, staged in LDS.

template <int H, int C>
__global__ __launch_bounds__(256) void k_agg(const int* __restrict__ rp, const int* __restrict__ col,
                                             const ushort_t* __restrict__ hbf,
                                             const float* __restrict__ asg,
                                             const float* __restrict__ adg,
                                             const float* __restrict__ bias,
                                             float* __restrict__ out, int N) {
  constexpr int HC = H * C;
  __shared__ float shp[4][64 * H];
  int lane = threadIdx.x & 63;
  int wv = threadIdx.x >> 6;
  int n = blockIdx.x * 4 + wv;
  if (n >= N) return;
  int hd = (H == 4) ? (lane >> 4) : 0;

  float d0 = 0.f, d1 = 0.f, d2 = 0.f, d3 = 0.f;
  if (H == 4) {
    float4 t = *(const float4*)(adg + (size_t)n * 4);
    d0 = t.x; d1 = t.y; d2 = t.z; d3 = t.w;
  } else {
    d0 = adg[n];
  }

  int s0 = rp[n], s1 = rp[n + 1];
  float m0 = -1e30f, m1 = -1e30f, m2 = -1e30f, m3 = -1e30f;
  float denom = 0.f, a0 = 0.f, a1 = 0.f;

  for (int base = s0; base < s1; base += 64) {
    int lim = s1 - base; if (lim > 64) lim = 64;
    int j = base + lane;
    bool valid = j < s1;
    int cj = valid ? col[j] : 0;

    float e0, e1 = -1e30f, e2 = -1e30f, e3 = -1e30f;
    if (H == 4) {
      float4 t = *(const float4*)(asg + (size_t)cj * 4);
      e0 = valid ? leaky(t.x + d0) : -1e30f;
      e1 = valid ? leaky(t.y + d1) : -1e30f;
      e2 = valid ? leaky(t.z + d2) : -1e30f;
      e3 = valid ? leaky(t.w + d3) : -1e30f;
    } else {
      float t = asg[cj];
      e0 = valid ? leaky(t + d0) : -1e30f;
    }

    // wave-max per head
    float c0 = e0, c1 = e1, c2 = e2, c3 = e3;
#pragma unroll
    for (int msk = 1; msk < 64; msk <<= 1) {
      c0 = fmaxf(c0, __shfl_xor(c0, msk));
      if (H == 4) {
        c1 = fmaxf(c1, __shfl_xor(c1, msk));
        c2 = fmaxf(c2, __shfl_xor(c2, msk));
        c3 = fmaxf(c3, __shfl_xor(c3, msk));
      }
    }
    float n0 = fmaxf(m0, c0), n1 = fmaxf(m1, c1), n2 = fmaxf(m2, c2), n3 = fmaxf(m3, c3);

    // rescale running accumulators (own head)
    float mo = (H == 4) ? sel4(hd, m0, m1, m2, m3) : m0;
    float nn = (H == 4) ? sel4(hd, n0, n1, n2, n3) : n0;
    float sc = __expf(mo - nn);
    denom *= sc; a0 *= sc; a1 *= sc;
    m0 = n0; m1 = n1; m2 = n2; m3 = n3;

    // p for this lane's edge, all heads, staged to LDS
    if (H == 4) {
      float4 p;
      p.x = __expf(e0 - n0); p.y = __expf(e1 - n1);
      p.z = __expf(e2 - n2); p.w = __expf(e3 - n3);
      *(float4*)&shp[wv][lane * 4] = p;
    } else {
      shp[wv][lane] = __expf(e0 - n0);
    }
    __builtin_amdgcn_sched_barrier(0);

    for (int i = 0; i < lim; ++i) {
      int s = __shfl(cj, i);
      float p = (H == 4) ? shp[wv][i * 4 + hd] : shp[wv][i];
      if (H == 4) {
        uint hv = *(const uint*)(hbf + (size_t)s * HC + lane * 2);
        a0 += p * bflo(hv);
        a1 += p * bfhi(hv);
      } else {
        float hx = bflo((uint)hbf[(size_t)s * HC + lane] << 0) ; // placeholder, replaced below
        (void)hx;
        uint hv = (uint)hbf[(size_t)s * HC + lane];
        a0 += p * __uint_as_float(hv << 16);
      }
      denom += p;
    }
  }

  float inv = 1.f / denom;
  if (H == 4) {
    float2 o;
    o.x = a0 * inv + bias[lane * 2];
    o.y = a1 * inv + bias[lane * 2 + 1];
    *(float2*)(out + (size_t)n * HC + lane * 2) = o;
  } else {
    out[(size_t)n * HC + lane] = a0 * inv + bias[lane];
  }
}

// ---------------- BatchNorm (training-mode batch stats) ----------------

__global__ __launch_bounds__(512) void k_bnstats1(const float* __restrict__ t,
                                                  float* __restrict__ p1, float* __restrict__ p2,
                                                  int N) {
  __shared__ float ls[4][128], ls2[4][128];
  int c = threadIdx.x & 127, q = threadIdx.x >> 7;
  float s = 0.f, s2 = 0.f;
  for (int r = blockIdx.x * 4 + q; r < N; r += gridDim.x * 4) {
    float v = t[(size_t)r * 128 + c];
    s += v;
    s2 += v * v;
  }
  ls[q][c] = s; ls2[q][c] = s2;
  __syncthreads();
  if (q == 0) {
    s = ls[0][c] + ls[1][c] + ls[2][c] + ls[3][c];
    s2 = ls2[0][c] + ls2[1][c] + ls2[2][c] + ls2[3][c];
    p1[blockIdx.x * 128 + c] = s;
    p2[blockIdx.x * 128 + c] = s2;
  }
}

__global__ void k_bnstats2(const float* __restrict__ p1, const float* __restrict__ p2,
                           float* __restrict__ mu, float* __restrict__ rstd, int G, int N) {
  int c = threadIdx.x;
  float s = 0.f, s2 = 0.f;
  for (int b = 0; b < G; ++b) { s += p1[b * 128 + c]; s2 += p2[b * 128 + c]; }
  float m = s / (float)N;
  float var = s2 / (float)N - m * m;
  mu[c] = m;
  rstd[c] = rsqrtf(var + 1e-5f);
}

__global__ __launch_bounds__(256) void k_bnapply1(const float* __restrict__ t,
                                                  const float* __restrict__ mu,
                                                  const float* __restrict__ rstd,
                                                  const float* __restrict__ g,
                                                  const float* __restrict__ be,
                                                  float* __restrict__ o, int n4) {
  int i = blockIdx.x * 256 + threadIdx.x;
  if (i >= n4) return;
  float4 v = ((const float4*)t)[i];
  int c = (i & 31) * 4;
  float4 r;
  r.x = fmaxf((v.x - mu[c + 0]) * rstd[c + 0] * g[c + 0] + be[c + 0], 0.f);
  r.y = fmaxf((v.y - mu[c + 1]) * rstd[c + 1] * g[c + 1] + be[c + 1], 0.f);
  r.z = fmaxf((v.z - mu[c + 2]) * rstd[c + 2] * g[c + 2] + be[c + 2], 0.f);
  r.w = fmaxf((v.w - mu[c + 3]) * rstd[c + 3] * g[c + 3] + be[c + 3], 0.f);
  ((float4*)o)[i] = r;
}

__global__ __launch_bounds__(256) void k_bnapply2(float* __restrict__ t,
                                                  const float* __restrict__ skip,
                                                  const float* __restrict__ out1,
                                                  const float* __restrict__ mu,
                                                  const float* __restrict__ rstd,
                                                  const float* __restrict__ g,
                                                  const float* __restrict__ be, int n4) {
  int i = blockIdx.x * 256 + threadIdx.x;
  if (i >= n4) return;
  float4 v = ((const float4*)t)[i];
  float4 sk = ((const float4*)skip)[i];
  float4 o1 = ((const float4*)out1)[i];
  int c = (i & 31) * 4;
  float4 r;
  r.x = o1.x + fmaxf((v.x - mu[c + 0]) * rstd[c + 0] * g[c + 0] + be[c + 0] + 0.5f * sk.x, 0.f);
  r.y = o1.y + fmaxf((v.y - mu[c + 1]) * rstd[c + 1] * g[c + 1] + be[c + 1] + 0.5f * sk.y, 0.f);
  r.z = o1.z + fmaxf((v.z - mu[c + 2]) * rstd[c + 2] * g[c + 2] + be[c + 2] + 0.5f * sk.z, 0.f);
  r.w = o1.w + fmaxf((v.w - mu[c + 3]) * rstd[c + 3] * g[c + 3] + be[c + 3] + 0.5f * sk.w, 0.f);
  ((float4*)t)[i] = r;
}

// ---------------------------------------------------------------------------

extern "C" void kernel_launch(void* const* d_in, const int* in_sizes, int n_in,
                              void* d_out, int out_size, void* d_ws, size_t ws_size,
                              hipStream_t stream) {
  const float* x = (const float*)d_in[0];
  const int* ei = (const int*)d_in[1];
  const float* W[4]  = {(const float*)d_in[2], (const float*)d_in[6],
                        (const float*)d_in[10], (const float*)d_in[14]};
  const float* AS[4] = {(const float*)d_in[3], (const float*)d_in[7],
                        (const float*)d_in[11], (const float*)d_in[15]};
  const float* AD[4] = {(const float*)d_in[4], (const float*)d_in[8],
                        (const float*)d_in[12], (const float*)d_in[16]};
  const float* B[4]  = {(const float*)d_in[5], (const float*)d_in[9],
                        (const float*)d_in[13], (const float*)d_in[17]};
  const float* g1 = (const float*)d_in[18];
  const float* be1 = (const float*)d_in[19];
  const float* g2 = (const float*)d_in[20];
  const float* be2 = (const float*)d_in[21];

  const int N = in_sizes[0] / 128;
  const int ER = in_sizes[1] / 2;
  const int ET = ER + N;

  char* ws = (char*)d_ws;
  size_t off = 0;
  auto carve = [&](size_t bytes) {
    size_t o = off;
    off = (off + bytes + 255) & ~(size_t)255;
    return (void*)(ws + o);
  };
  int* rowptr   = (int*)carve((size_t)(N + 1) * 4);
  int* fill     = (int*)carve((size_t)N * 4);
  int* col      = (int*)carve((size_t)ET * 4);
  int* bsums    = (int*)carve(64 * 4);
  float* asg    = (float*)carve((size_t)N * 4 * 4);
  float* adg    = (float*)carve((size_t)N * 4 * 4);
  ushort_t* hbf = (ushort_t*)carve((size_t)N * 128 * 2);
  float* skipb  = (float*)carve((size_t)N * 128 * 4);
  float* out1b  = (float*)carve((size_t)N * 128 * 4);
  float* tmpf   = (float*)carve((size_t)N * 128 * 4);
  float* p1     = (float*)carve(128 * 128 * 4);
  float* p2     = (float*)carve(128 * 128 * 4);
  float* mu     = (float*)carve(128 * 4);
  float* rstd   = (float*)carve(128 * 4);
  (void)ws_size;

  const int nb = (N + 2047) / 2048;
  const int gE = (ET + 255) / 256;
  const int gN4 = (N + 3) / 4;
  const int gG = (N + 63) / 64;
  const int n4 = N * 32;
  const int gP = (n4 + 255) / 256;

  // ---- CSR build ----
  hipMemsetAsync(fill, 0, (size_t)N * 4, stream);
  k_deg<<<gE, 256, 0, stream>>>(ei, ER, ET, fill);
  k_scan1<<<nb, 256, 0, stream>>>(fill, rowptr, bsums, N);
  k_scan2<<<1, 1, 0, stream>>>(bsums, nb);
  k_scan3<<<(N + 256) / 256, 256, 0, stream>>>(rowptr, bsums, N, ET);
  hipMemsetAsync(fill, 0, (size_t)N * 4, stream);
  k_scatter<<<gE, 256, 0, stream>>>(ei, ER, ET, rowptr, fill, col);

  // ---- layer 0: x -> skipb ----
  k_gemm<128, 4><<<gG, 256, 0, stream>>>(x, W[0], AS[0], AD[0], hbf, asg, adg, N);
  k_agg<4, 32><<<gN4, 256, 0, stream>>>(rowptr, col, hbf, asg, adg, B[0], skipb, N);

  // ---- layer 1: skipb -> tmpf -> bn/relu -> out1b ----
  k_gemm<128, 4><<<gG, 256, 0, stream>>>(skipb, W[1], AS[1], AD[1], hbf, asg, adg, N);
  k_agg<4, 32><<<gN4, 256, 0, stream>>>(rowptr, col, hbf, asg, adg, B[1], tmpf, N);
  k_bnstats1<<<128, 512, 0, stream>>>(tmpf, p1, p2, N);
  k_bnstats2<<<1, 128, 0, stream>>>(p1, p2, mu, rstd, 128, N);
  k_bnapply1<<<gP, 256, 0, stream>>>(tmpf, mu, rstd, g1, be1, out1b, n4);

  // ---- layer 2: out1b -> tmpf -> bn + 0.5*skip, relu, + out1 -> tmpf ----
  k_gemm<128, 4><<<gG, 256, 0, stream>>>(out1b, W[2], AS[2], AD[2], hbf, asg, adg, N);
  k_agg<4, 32><<<gN4, 256, 0, stream>>>(rowptr, col, hbf, asg, adg, B[2], tmpf, N);
  k_bnstats1<<<128, 512, 0, stream>>>(tmpf, p1, p2, N);
  k_bnstats2<<<1, 128, 0, stream>>>(p1, p2, mu, rstd, 128, N);
  k_bnapply2<<<gP, 256, 0, stream>>>(tmpf, skipb, out1b, mu, rstd, g2, be2, n4);

  // ---- layer 3: tmpf -> d_out (H=1, C=64) ----
  k_gemm<64, 1><<<gG, 256, 0, stream>>>(tmpf, W[3], AS[3], AD[3], hbf, asg, adg, N);
  k_agg<1, 64><<<gN4, 256, 0, stream>>>(rowptr, col, hbf, asg, adg, B[3], (float*)d_out, N);
}

// Round 6
// 1096.890 us; speedup vs baseline: 1.6315x; 1.1281x over previous
//
#include <hip/hip_runtime.h>
#include <cstdint>
#include <cstddef>

// ---------------------------------------------------------------------------
// GAT 4-layer network.
// Per layer: MFMA GEMM (split-bf16 x3 products == fp32 precision) with fused
//            alpha dots + bf16 h store -> CSR segment softmax aggregation
//            (no-max softmax, bf16 gather, shfl col broadcast).
// CSR built per launch. Producers write A as (hi,lo) bf16 pairs for the next
// layer's GEMM. skip/out1 carried as packed bf16 (hi only) to fit ws budget.
// ---------------------------------------------------------------------------

typedef unsigned int uint;
typedef unsigned short ushort_t;
typedef __attribute__((ext_vector_type(8))) short bf16x8_t;   // 8 bf16 = 4 VGPR
typedef __attribute__((ext_vector_type(4))) float f32x4_t;

__device__ __forceinline__ float leaky(float e) { return e < 0.f ? 0.2f * e : e; }
__device__ __forceinline__ float bflo(uint u) { return __uint_as_float(u << 16); }
__device__ __forceinline__ float bfhi(uint u) { return __uint_as_float(u & 0xffff0000u); }
__device__ __forceinline__ ushort_t f2bf(float f) {
  uint u = __float_as_uint(f);
  u += 0x7fffu + ((u >> 16) & 1u);           // round-to-nearest-even
  return (ushort_t)(u >> 16);
}
__device__ __forceinline__ float bf2f(ushort_t h) { return __uint_as_float((uint)h << 16); }
__device__ __forceinline__ uint pack2(float a, float b) {
  return (uint)f2bf(a) | ((uint)f2bf(b) << 16);
}

// ---------------- CSR build ----------------

__global__ __launch_bounds__(256) void k_deg(const int* __restrict__ ei, int ER, int ET,
                                             int* __restrict__ deg) {
  int e = blockIdx.x * 256 + threadIdx.x;
  if (e >= ET) return;
  int d = (e < ER) ? ei[ER + e] : (e - ER);
  atomicAdd(&deg[d], 1);
}

__global__ __launch_bounds__(256) void k_scan1(const int* __restrict__ deg, int* __restrict__ rp,
                                               int* __restrict__ bsums, int n) {
  __shared__ int sh[256];
  int tid = threadIdx.x;
  int base = blockIdx.x * 2048 + tid * 8;
  int pre[8];
  int s = 0;
#pragma unroll
  for (int j = 0; j < 8; ++j) {
    int idx = base + j;
    int v = (idx < n) ? deg[idx] : 0;
    pre[j] = s;
    s += v;
  }
  sh[tid] = s;
  __syncthreads();
  for (int d = 1; d < 256; d <<= 1) {
    int t = (tid >= d) ? sh[tid - d] : 0;
    __syncthreads();
    if (tid >= d) sh[tid] += t;
    __syncthreads();
  }
  int excl = sh[tid] - s;
#pragma unroll
  for (int j = 0; j < 8; ++j) {
    int idx = base + j;
    if (idx < n) rp[idx] = excl + pre[j];
  }
  if (tid == 255) bsums[blockIdx.x] = sh[255];
}

__global__ void k_scan2(int* bsums, int nb) {
  for (int i = 1; i < nb; ++i) bsums[i] += bsums[i - 1];
}

__global__ __launch_bounds__(256) void k_scan3(int* __restrict__ rp, const int* __restrict__ bsums,
                                               int n, int ET) {
  int i = blockIdx.x * 256 + threadIdx.x;
  if (i > n) return;
  if (i == n) { rp[n] = ET; return; }
  int b = i >> 11;
  if (b > 0) rp[i] += bsums[b - 1];
}

__global__ __launch_bounds__(256) void k_scatter(const int* __restrict__ ei, int ER, int ET,
                                                 const int* __restrict__ rp, int* __restrict__ fill,
                                                 int* __restrict__ col) {
  int e = blockIdx.x * 256 + threadIdx.x;
  if (e >= ET) return;
  int s, d;
  if (e < ER) { s = ei[e]; d = ei[ER + e]; } else { s = e - ER; d = s; }
  int pos = rp[d] + atomicAdd(&fill[d], 1);
  col[pos] = s;
}

// ---------------- weight prep: W^T split into bf16 hi/lo ----------------
// Wthi/Wtlo layout: per-layer base l*16384, then [j][k] row-major, k padded to 128.

__global__ __launch_bounds__(256) void k_prepW(const float* __restrict__ W0,
                                               const float* __restrict__ W1,
                                               const float* __restrict__ W2,
                                               const float* __restrict__ W3,
                                               ushort_t* __restrict__ Wthi,
                                               ushort_t* __restrict__ Wtlo) {
  int id = blockIdx.x * 256 + threadIdx.x;
  int l = id >> 14;
  if (l >= 4) return;
  int t = id & 16383;
  int j = t >> 7, k = t & 127;
  const float* W = (l == 0) ? W0 : (l == 1) ? W1 : (l == 2) ? W2 : W3;
  int cols = (l == 3) ? 64 : 128;
  if (j >= cols) return;
  float v = W[(size_t)k * cols + j];
  ushort_t hi = f2bf(v);
  float rem = v - bf2f(hi);
  Wthi[(size_t)l * 16384 + j * 128 + k] = hi;
  Wtlo[(size_t)l * 16384 + j * 128 + k] = f2bf(rem);
}

// ---------------- split fp32 -> bf16 hi/lo (layer-0 input) ----------------

__global__ __launch_bounds__(256) void k_split(const float* __restrict__ in,
                                               uint* __restrict__ hi2, uint* __restrict__ lo2,
                                               int n4) {
  int i = blockIdx.x * 256 + threadIdx.x;
  if (i >= n4) return;
  float4 v = ((const float4*)in)[i];
  ushort_t hx = f2bf(v.x), hy = f2bf(v.y), hz = f2bf(v.z), hw = f2bf(v.w);
  uint2 h = make_uint2((uint)hx | ((uint)hy << 16), (uint)hz | ((uint)hw << 16));
  uint2 l = make_uint2(pack2(v.x - bf2f(hx), v.y - bf2f(hy)),
                       pack2(v.z - bf2f(hz), v.w - bf2f(hw)));
  ((uint2*)hi2)[i] = h;
  ((uint2*)lo2)[i] = l;
}

// ---------------- MFMA GEMM: h_bf16[N,COLS] = (Ahi+Alo)[N,128] @ W[128,COLS]
// + alpha_src/dst dots. Wave = 16 rows; block = 4 waves = 64 rows.
// v_mfma_f32_16x16x32_bf16: A row=lane&15, k=(lane>>4)*8+e;
//                           B col=lane&15, k=(lane>>4)*8+e;  C/D col=lane&15, row=(lane>>4)*4+reg.

template <int COLS, int H>
__global__ __launch_bounds__(256) void k_mm(const ushort_t* __restrict__ Ahi,
                                            const ushort_t* __restrict__ Alo,
                                            const ushort_t* __restrict__ Wthi,
                                            const ushort_t* __restrict__ Wtlo,
                                            const float* __restrict__ aS,
                                            const float* __restrict__ aD,
                                            ushort_t* __restrict__ hbf,
                                            float* __restrict__ asg,
                                            float* __restrict__ adg, int N) {
  constexpr int NB = COLS / 16;
  __shared__ __align__(16) ushort_t sWhi[COLS * 136];
  __shared__ __align__(16) ushort_t sWlo[COLS * 136];
  int tid = threadIdx.x;
  int lane = tid & 63, wv = tid >> 6;
  int lj = lane & 15, lg = lane >> 4;
  int r0 = blockIdx.x * 64 + wv * 16;

  // stage W^T hi/lo into padded LDS (row pitch 136 elems = 272 B).
  // uint4 = 8 ushorts -> 16 segments of 8 elements per 128-wide row.
  for (int idx = tid; idx < COLS * 16; idx += 256) {
    int j = idx >> 4, seg = idx & 15;
    uint4 vh = *(const uint4*)(Wthi + (size_t)j * 128 + seg * 8);
    uint4 vl = *(const uint4*)(Wtlo + (size_t)j * 128 + seg * 8);
    *(uint4*)&sWhi[j * 136 + seg * 8] = vh;
    *(uint4*)&sWlo[j * 136 + seg * 8] = vl;
  }
  __syncthreads();

  f32x4_t acc[NB];
#pragma unroll
  for (int cb = 0; cb < NB; ++cb) acc[cb] = (f32x4_t){0.f, 0.f, 0.f, 0.f};

  int rowc = r0 + lj; if (rowc >= N) rowc = N - 1;
  const ushort_t* apH = Ahi + (size_t)rowc * 128 + lg * 8;
  const ushort_t* apL = Alo + (size_t)rowc * 128 + lg * 8;

#pragma unroll
  for (int kc = 0; kc < 4; ++kc) {
    bf16x8_t ah = *(const bf16x8_t*)(apH + kc * 32);
    bf16x8_t al = *(const bf16x8_t*)(apL + kc * 32);
#pragma unroll
    for (int cb = 0; cb < NB; ++cb) {
      int boff = (cb * 16 + lj) * 136 + kc * 32 + lg * 8;
      bf16x8_t bh = *(const bf16x8_t*)&sWhi[boff];
      bf16x8_t bl = *(const bf16x8_t*)&sWlo[boff];
      acc[cb] = __builtin_amdgcn_mfma_f32_16x16x32_bf16(ah, bh, acc[cb], 0, 0, 0);
      acc[cb] = __builtin_amdgcn_mfma_f32_16x16x32_bf16(al, bh, acc[cb], 0, 0, 0);
      acc[cb] = __builtin_amdgcn_mfma_f32_16x16x32_bf16(ah, bl, acc[cb], 0, 0, 0);
    }
  }

  // ---- alpha dots: ps/pd per (row, head), reduce across the 16 j-lanes ----
  float asv[NB], adv[NB];
#pragma unroll
  for (int cb = 0; cb < NB; ++cb) {
    asv[cb] = aS[cb * 16 + lj];
    adv[cb] = aD[cb * 16 + lj];
  }
#pragma unroll
  for (int reg = 0; reg < 4; ++reg) {
    int row = r0 + lg * 4 + reg;
    if (H == 4) {
      float ps[4] = {0.f, 0.f, 0.f, 0.f}, pd[4] = {0.f, 0.f, 0.f, 0.f};
#pragma unroll
      for (int cb = 0; cb < NB; ++cb) {
        int h = cb >> 1;
        ps[h] += acc[cb][reg] * asv[cb];
        pd[h] += acc[cb][reg] * adv[cb];
      }
#pragma unroll
      for (int m = 1; m < 16; m <<= 1) {
#pragma unroll
        for (int h = 0; h < 4; ++h) {
          ps[h] += __shfl_xor(ps[h], m);
          pd[h] += __shfl_xor(pd[h], m);
        }
      }
      if (lj == 0 && row < N) {
        *(float4*)(asg + (size_t)row * 4) = make_float4(ps[0], ps[1], ps[2], ps[3]);
        *(float4*)(adg + (size_t)row * 4) = make_float4(pd[0], pd[1], pd[2], pd[3]);
      }
    } else {
      float ps = 0.f, pd = 0.f;
#pragma unroll
      for (int cb = 0; cb < NB; ++cb) {
        ps += acc[cb][reg] * asv[cb];
        pd += acc[cb][reg] * adv[cb];
      }
#pragma unroll
      for (int m = 1; m < 16; m <<= 1) {
        ps += __shfl_xor(ps, m);
        pd += __shfl_xor(pd, m);
      }
      if (lj == 0 && row < N) { asg[row] = ps; adg[row] = pd; }
    }
  }

  // ---- h bf16 store via LDS bounce (reuse sWhi after barrier) ----
  __syncthreads();
  ushort_t* bnc = sWhi + wv * (16 * 136);
#pragma unroll
  for (int cb = 0; cb < NB; ++cb)
#pragma unroll
    for (int reg = 0; reg < 4; ++reg)
      bnc[(lg * 4 + reg) * 136 + cb * 16 + lj] = f2bf(acc[cb][reg]);
  // wave-local LDS round-trip: compiler inserts lgkm waits
  constexpr int UPR = COLS / 8;          // 16B units per row
  constexpr int NPASS = 16 * UPR / 64;
#pragma unroll
  for (int p = 0; p < NPASS; ++p) {
    int u = p * 64 + lane;
    int rl = u / UPR, sg = u % UPR;
    if (r0 + rl < N)
      *(uint4*)(hbf + (size_t)(r0 + rl) * COLS + sg * 8) = *(const uint4*)&bnc[rl * 136 + sg * 8];
  }
}

// ---------------- aggregation: one wave per destination node ----------------
// No-max softmax (shift-invariant; logits O(10) -> no overflow).
// MODE 0: fp32 out. MODE 1: packed-bf16 out + (hi,lo) split for next GEMM.

template <int H, int C, int MODE>
__global__ __launch_bounds__(256) void k_agg(const int* __restrict__ rp, const int* __restrict__ col,
                                             const ushort_t* __restrict__ hbf,
                                             const float* __restrict__ asg,
                                             const float* __restrict__ adg,
                                             const float* __restrict__ bias,
                                             float* __restrict__ out,
                                             uint* __restrict__ outp,
                                             uint* __restrict__ ohi, uint* __restrict__ olo,
                                             int N) {
  constexpr int HC = H * C;
  __shared__ float shp[4][64 * H];
  int lane = threadIdx.x & 63;
  int wv = threadIdx.x >> 6;
  int n = blockIdx.x * 4 + wv;
  if (n >= N) return;
  int hd = (H == 4) ? (lane >> 4) : 0;

  float d0 = 0.f, d1 = 0.f, d2 = 0.f, d3 = 0.f;
  if (H == 4) {
    float4 t = *(const float4*)(adg + (size_t)n * 4);
    d0 = t.x; d1 = t.y; d2 = t.z; d3 = t.w;
  } else {
    d0 = adg[n];
  }

  int s0 = rp[n], s1 = rp[n + 1];
  float denom = 0.f, a0 = 0.f, a1 = 0.f;

  for (int base = s0; base < s1; base += 64) {
    int lim = s1 - base; if (lim > 64) lim = 64;
    int j = base + lane;
    bool valid = j < s1;
    int cj = valid ? col[j] : 0;

    if (H == 4) {
      float4 t = *(const float4*)(asg + (size_t)cj * 4);
      float4 p;
      p.x = valid ? __expf(leaky(t.x + d0)) : 0.f;
      p.y = valid ? __expf(leaky(t.y + d1)) : 0.f;
      p.z = valid ? __expf(leaky(t.z + d2)) : 0.f;
      p.w = valid ? __expf(leaky(t.w + d3)) : 0.f;
      *(float4*)&shp[wv][lane * 4] = p;
    } else {
      float t = asg[cj];
      shp[wv][lane] = valid ? __expf(leaky(t + d0)) : 0.f;
    }
    __builtin_amdgcn_sched_barrier(0);

    for (int i = 0; i < lim; ++i) {
      int s = __shfl(cj, i);
      float p = (H == 4) ? shp[wv][i * 4 + hd] : shp[wv][i];
      if (H == 4) {
        uint hv = *(const uint*)(hbf + (size_t)s * HC + lane * 2);
        a0 += p * bflo(hv);
        a1 += p * bfhi(hv);
      } else {
        uint hv = (uint)hbf[(size_t)s * HC + lane];
        a0 += p * __uint_as_float(hv << 16);
      }
      denom += p;
    }
  }

  float inv = 1.f / denom;
  if (H == 4) {
    float o0 = a0 * inv + bias[lane * 2];
    float o1 = a1 * inv + bias[lane * 2 + 1];
    if (MODE == 0) {
      *(float2*)(out + (size_t)n * HC + lane * 2) = make_float2(o0, o1);
    } else {
      ushort_t hx = f2bf(o0), hy = f2bf(o1);
      uint hw = (uint)hx | ((uint)hy << 16);
      outp[(size_t)n * 64 + lane] = hw;                       // skip (bf16 hi)
      ohi[(size_t)n * 64 + lane] = hw;                        // next-GEMM hi
      olo[(size_t)n * 64 + lane] = pack2(o0 - bf2f(hx), o1 - bf2f(hy));
    }
  } else {
    out[(size_t)n * HC + lane] = a0 * inv + bias[lane];
  }
}

// ---------------- BatchNorm (training-mode batch stats) ----------------

__global__ __launch_bounds__(512) void k_bnstats1(const float* __restrict__ t,
                                                  float* __restrict__ p1, float* __restrict__ p2,
                                                  int N) {
  __shared__ float ls[4][128], ls2[4][128];
  int c = threadIdx.x & 127, q = threadIdx.x >> 7;
  float s = 0.f, s2 = 0.f;
  for (int r = blockIdx.x * 4 + q; r < N; r += gridDim.x * 4) {
    float v = t[(size_t)r * 128 + c];
    s += v;
    s2 += v * v;
  }
  ls[q][c] = s; ls2[q][c] = s2;
  __syncthreads();
  if (q == 0) {
    s = ls[0][c] + ls[1][c] + ls[2][c] + ls[3][c];
    s2 = ls2[0][c] + ls2[1][c] + ls2[2][c] + ls2[3][c];
    p1[blockIdx.x * 128 + c] = s;
    p2[blockIdx.x * 128 + c] = s2;
  }
}

__global__ void k_bnstats2(const float* __restrict__ p1, const float* __restrict__ p2,
                           float* __restrict__ mu, float* __restrict__ rstd, int G, int N) {
  int c = threadIdx.x;
  float s = 0.f, s2 = 0.f;
  for (int b = 0; b < G; ++b) { s += p1[b * 128 + c]; s2 += p2[b * 128 + c]; }
  float m = s / (float)N;
  float var = s2 / (float)N - m * m;
  mu[c] = m;
  rstd[c] = rsqrtf(var + 1e-5f);
}

// out1 = relu(bn(t)); writes out1 as packed bf16 + (hi,lo) split (next GEMM's A)
__global__ __launch_bounds__(256) void k_bnapply1(const float* __restrict__ t,
                                                  const float* __restrict__ mu,
                                                  const float* __restrict__ rstd,
                                                  const float* __restrict__ g,
                                                  const float* __restrict__ be,
                                                  uint* __restrict__ o1p,
                                                  uint* __restrict__ ohi, uint* __restrict__ olo,
                                                  int n4) {
  int i = blockIdx.x * 256 + threadIdx.x;
  if (i >= n4) return;
  float4 v = ((const float4*)t)[i];
  int c = (i & 31) * 4;
  float4 r;
  r.x = fmaxf((v.x - mu[c + 0]) * rstd[c + 0] * g[c + 0] + be[c + 0], 0.f);
  r.y = fmaxf((v.y - mu[c + 1]) * rstd[c + 1] * g[c + 1] + be[c + 1], 0.f);
  r.z = fmaxf((v.z - mu[c + 2]) * rstd[c + 2] * g[c + 2] + be[c + 2], 0.f);
  r.w = fmaxf((v.w - mu[c + 3]) * rstd[c + 3] * g[c + 3] + be[c + 3], 0.f);
  ushort_t hx = f2bf(r.x), hy = f2bf(r.y), hz = f2bf(r.z), hw = f2bf(r.w);
  uint2 h = make_uint2((uint)hx | ((uint)hy << 16), (uint)hz | ((uint)hw << 16));
  ((uint2*)o1p)[i] = h;
  ((uint2*)ohi)[i] = h;
  ((uint2*)olo)[i] = make_uint2(pack2(r.x - bf2f(hx), r.y - bf2f(hy)),
                                pack2(r.z - bf2f(hz), r.w - bf2f(hw)));
}

// out2 = relu(bn(t) + 0.5*skip); sum = out1 + out2 -> (hi,lo) split only
__global__ __launch_bounds__(256) void k_bnapply2(const float* __restrict__ t,
                                                  const uint* __restrict__ skp,
                                                  const uint* __restrict__ o1p,
                                                  const float* __restrict__ mu,
                                                  const float* __restrict__ rstd,
                                                  const float* __restrict__ g,
                                                  const float* __restrict__ be,
                                                  uint* __restrict__ ohi, uint* __restrict__ olo,
                                                  int n4) {
  int i = blockIdx.x * 256 + threadIdx.x;
  if (i >= n4) return;
  float4 v = ((const float4*)t)[i];
  uint2 sku = ((const uint2*)skp)[i];
  uint2 o1u = ((const uint2*)o1p)[i];
  int c = (i & 31) * 4;
  float4 r;
  r.x = bflo(o1u.x) + fmaxf((v.x - mu[c + 0]) * rstd[c + 0] * g[c + 0] + be[c + 0] + 0.5f * bflo(sku.x), 0.f);
  r.y = bfhi(o1u.x) + fmaxf((v.y - mu[c + 1]) * rstd[c + 1] * g[c + 1] + be[c + 1] + 0.5f * bfhi(sku.x), 0.f);
  r.z = bflo(o1u.y) + fmaxf((v.z - mu[c + 2]) * rstd[c + 2] * g[c + 2] + be[c + 2] + 0.5f * bflo(sku.y), 0.f);
  r.w = bfhi(o1u.y) + fmaxf((v.w - mu[c + 3]) * rstd[c + 3] * g[c + 3] + be[c + 3] + 0.5f * bfhi(sku.y), 0.f);
  ushort_t hx = f2bf(r.x), hy = f2bf(r.y), hz = f2bf(r.z), hw = f2bf(r.w);
  ((uint2*)ohi)[i] = make_uint2((uint)hx | ((uint)hy << 16), (uint)hz | ((uint)hw << 16));
  ((uint2*)olo)[i] = make_uint2(pack2(r.x - bf2f(hx), r.y - bf2f(hy)),
                                pack2(r.z - bf2f(hz), r.w - bf2f(hw)));
}

// ---------------------------------------------------------------------------

extern "C" void kernel_launch(void* const* d_in, const int* in_sizes, int n_in,
                              void* d_out, int out_size, void* d_ws, size_t ws_size,
                              hipStream_t stream) {
  const float* x = (const float*)d_in[0];
  const int* ei = (const int*)d_in[1];
  const float* W[4]  = {(const float*)d_in[2], (const float*)d_in[6],
                        (const float*)d_in[10], (const float*)d_in[14]};
  const float* AS[4] = {(const float*)d_in[3], (const float*)d_in[7],
                        (const float*)d_in[11], (const float*)d_in[15]};
  const float* AD[4] = {(const float*)d_in[4], (const float*)d_in[8],
                        (const float*)d_in[12], (const float*)d_in[16]};
  const float* B[4]  = {(const float*)d_in[5], (const float*)d_in[9],
                        (const float*)d_in[13], (const float*)d_in[17]};
  const float* g1 = (const float*)d_in[18];
  const float* be1 = (const float*)d_in[19];
  const float* g2 = (const float*)d_in[20];
  const float* be2 = (const float*)d_in[21];

  const int N = in_sizes[0] / 128;
  const int ER = in_sizes[1] / 2;
  const int ET = ER + N;

  char* ws = (char*)d_ws;
  size_t off = 0;
  auto carve = [&](size_t bytes) {
    size_t o = off;
    off = (off + bytes + 255) & ~(size_t)255;
    return (void*)(ws + o);
  };
  int* rowptr     = (int*)carve((size_t)(N + 1) * 4);
  int* col        = (int*)carve((size_t)ET * 4);
  int* bsums      = (int*)carve(64 * 4);
  float* asg      = (float*)carve((size_t)N * 4 * 4);
  float* adg      = (float*)carve((size_t)N * 4 * 4);
  ushort_t* hbf   = (ushort_t*)carve((size_t)N * 128 * 2);
  ushort_t* ahi   = (ushort_t*)carve((size_t)N * 128 * 2);
  ushort_t* alo   = (ushort_t*)carve((size_t)N * 128 * 2);
  uint* skipb     = (uint*)carve((size_t)N * 64 * 4);     // packed bf16 [N,128]
  uint* out1b     = (uint*)carve((size_t)N * 64 * 4);     // packed bf16 [N,128]
  float* tbuf     = (float*)carve((size_t)N * 128 * 4);
  ushort_t* Wthi  = (ushort_t*)carve(4 * 16384 * 2);
  ushort_t* Wtlo  = (ushort_t*)carve(4 * 16384 * 2);
  float* p1       = (float*)carve(128 * 128 * 4);
  float* p2       = (float*)carve(128 * 128 * 4);
  float* mu       = (float*)carve(128 * 4);
  float* rstd     = (float*)carve(128 * 4);
  int* fill       = (int*)asg;   // alias: fill dead before asg first written (k_mm L0)
  (void)ws_size;

  const int nb = (N + 2047) / 2048;
  const int gE = (ET + 255) / 256;
  const int gN4 = (N + 3) / 4;
  const int gM = (N + 63) / 64;
  const int n4 = N * 32;
  const int gP = (n4 + 255) / 256;

  // ---- CSR build + weight prep + input split ----
  hipMemsetAsync(fill, 0, (size_t)N * 4, stream);
  k_deg<<<gE, 256, 0, stream>>>(ei, ER, ET, fill);
  k_scan1<<<nb, 256, 0, stream>>>(fill, rowptr, bsums, N);
  k_scan2<<<1, 1, 0, stream>>>(bsums, nb);
  k_scan3<<<(N + 256) / 256, 256, 0, stream>>>(rowptr, bsums, N, ET);
  hipMemsetAsync(fill, 0, (size_t)N * 4, stream);
  k_scatter<<<gE, 256, 0, stream>>>(ei, ER, ET, rowptr, fill, col);
  k_prepW<<<256, 256, 0, stream>>>(W[0], W[1], W[2], W[3], Wthi, Wtlo);
  k_split<<<gP, 256, 0, stream>>>(x, (uint*)ahi, (uint*)alo, n4);

  // ---- layer 0: x -> skipb(bf16) + hi/lo for layer-1 GEMM ----
  k_mm<128, 4><<<gM, 256, 0, stream>>>(ahi, alo, Wthi, Wtlo, AS[0], AD[0], hbf, asg, adg, N);
  k_agg<4, 32, 1><<<gN4, 256, 0, stream>>>(rowptr, col, hbf, asg, adg, B[0], nullptr,
                                           skipb, (uint*)ahi, (uint*)alo, N);

  // ---- layer 1 ----
  k_mm<128, 4><<<gM, 256, 0, stream>>>(ahi, alo, Wthi + 16384, Wtlo + 16384, AS[1], AD[1],
                                       hbf, asg, adg, N);
  k_agg<4, 32, 0><<<gN4, 256, 0, stream>>>(rowptr, col, hbf, asg, adg, B[1], tbuf,
                                           nullptr, nullptr, nullptr, N);
  k_bnstats1<<<128, 512, 0, stream>>>(tbuf, p1, p2, N);
  k_bnstats2<<<1, 128, 0, stream>>>(p1, p2, mu, rstd, 128, N);
  k_bnapply1<<<gP, 256, 0, stream>>>(tbuf, mu, rstd, g1, be1, out1b, (uint*)ahi, (uint*)alo, n4);

  // ---- layer 2 ----
  k_mm<128, 4><<<gM, 256, 0, stream>>>(ahi, alo, Wthi + 2 * 16384, Wtlo + 2 * 16384, AS[2], AD[2],
                                       hbf, asg, adg, N);
  k_agg<4, 32, 0><<<gN4, 256, 0, stream>>>(rowptr, col, hbf, asg, adg, B[2], tbuf,
                                           nullptr, nullptr, nullptr, N);
  k_bnstats1<<<128, 512, 0, stream>>>(tbuf, p1, p2, N);
  k_bnstats2<<<1, 128, 0, stream>>>(p1, p2, mu, rstd, 128, N);
  k_bnapply2<<<gP, 256, 0, stream>>>(tbuf, skipb, out1b, mu, rstd, g2, be2,
                                     (uint*)ahi, (uint*)alo, n4);

  // ---- layer 3: -> d_out (H=1, C=64) ----
  k_mm<64, 1><<<gM, 256, 0, stream>>>(ahi, alo, Wthi + 3 * 16384, Wtlo + 3 * 16384, AS[3], AD[3],
                                      hbf, asg, adg, N);
  k_agg<1, 64, 0><<<gN4, 256, 0, stream>>>(rowptr, col, hbf, asg, adg, B[3], (float*)d_out,
                                           nullptr, nullptr, nullptr, N);
}

// Round 10
// 916.247 us; speedup vs baseline: 1.9531x; 1.1972x over previous
//
#include <hip/hip_runtime.h>
#include <cstdint>
#include <cstddef>

// ---------------------------------------------------------------------------
// GAT 4-layer network.
// Per layer: MFMA GEMM (split-bf16 x3 products == fp32 precision) with fused
//            alpha dots + bf16 h store -> CSR segment softmax aggregation
//            (no-max softmax, wide 16B/lane gather: 4 edges/iter via 16-lane
//            groups, cross-group shfl reduce).
// CSR built per launch. Producers write A as (hi,lo) bf16 pairs for the next
// layer's GEMM. skip/out1 carried as packed bf16 (hi only).
// ---------------------------------------------------------------------------

typedef unsigned int uint;
typedef unsigned short ushort_t;
typedef __attribute__((ext_vector_type(8))) short bf16x8_t;   // 8 bf16 = 4 VGPR
typedef __attribute__((ext_vector_type(4))) float f32x4_t;

__device__ __forceinline__ float leaky(float e) { return e < 0.f ? 0.2f * e : e; }
__device__ __forceinline__ float bflo(uint u) { return __uint_as_float(u << 16); }
__device__ __forceinline__ float bfhi(uint u) { return __uint_as_float(u & 0xffff0000u); }
__device__ __forceinline__ ushort_t f2bf(float f) {
  uint u = __float_as_uint(f);
  u += 0x7fffu + ((u >> 16) & 1u);           // round-to-nearest-even
  return (ushort_t)(u >> 16);
}
__device__ __forceinline__ float bf2f(ushort_t h) { return __uint_as_float((uint)h << 16); }
__device__ __forceinline__ uint pack2(float a, float b) {
  return (uint)f2bf(a) | ((uint)f2bf(b) << 16);
}

// ---------------- CSR build ----------------

__global__ __launch_bounds__(256) void k_deg(const int* __restrict__ ei, int ER, int ET,
                                             int* __restrict__ deg) {
  int e = blockIdx.x * 256 + threadIdx.x;
  if (e >= ET) return;
  int d = (e < ER) ? ei[ER + e] : (e - ER);
  atomicAdd(&deg[d], 1);
}

__global__ __launch_bounds__(256) void k_scan1(const int* __restrict__ deg, int* __restrict__ rp,
                                               int* __restrict__ bsums, int n) {
  __shared__ int sh[256];
  int tid = threadIdx.x;
  int base = blockIdx.x * 2048 + tid * 8;
  int pre[8];
  int s = 0;
#pragma unroll
  for (int j = 0; j < 8; ++j) {
    int idx = base + j;
    int v = (idx < n) ? deg[idx] : 0;
    pre[j] = s;
    s += v;
  }
  sh[tid] = s;
  __syncthreads();
  for (int d = 1; d < 256; d <<= 1) {
    int t = (tid >= d) ? sh[tid - d] : 0;
    __syncthreads();
    if (tid >= d) sh[tid] += t;
    __syncthreads();
  }
  int excl = sh[tid] - s;
#pragma unroll
  for (int j = 0; j < 8; ++j) {
    int idx = base + j;
    if (idx < n) rp[idx] = excl + pre[j];
  }
  if (tid == 255) bsums[blockIdx.x] = sh[255];
}

__global__ void k_scan2(int* bsums, int nb) {
  for (int i = 1; i < nb; ++i) bsums[i] += bsums[i - 1];
}

__global__ __launch_bounds__(256) void k_scan3(int* __restrict__ rp, const int* __restrict__ bsums,
                                               int n, int ET) {
  int i = blockIdx.x * 256 + threadIdx.x;
  if (i > n) return;
  if (i == n) { rp[n] = ET; return; }
  int b = i >> 11;
  if (b > 0) rp[i] += bsums[b - 1];
}

__global__ __launch_bounds__(256) void k_scatter(const int* __restrict__ ei, int ER, int ET,
                                                 const int* __restrict__ rp, int* __restrict__ fill,
                                                 int* __restrict__ col) {
  int e = blockIdx.x * 256 + threadIdx.x;
  if (e >= ET) return;
  int s, d;
  if (e < ER) { s = ei[e]; d = ei[ER + e]; } else { s = e - ER; d = s; }
  int pos = rp[d] + atomicAdd(&fill[d], 1);
  col[pos] = s;
}

// ---------------- weight prep: W^T split into bf16 hi/lo ----------------

__global__ __launch_bounds__(256) void k_prepW(const float* __restrict__ W0,
                                               const float* __restrict__ W1,
                                               const float* __restrict__ W2,
                                               const float* __restrict__ W3,
                                               ushort_t* __restrict__ Wthi,
                                               ushort_t* __restrict__ Wtlo) {
  int id = blockIdx.x * 256 + threadIdx.x;
  int l = id >> 14;
  if (l >= 4) return;
  int t = id & 16383;
  int j = t >> 7, k = t & 127;
  const float* W = (l == 0) ? W0 : (l == 1) ? W1 : (l == 2) ? W2 : W3;
  int cols = (l == 3) ? 64 : 128;
  if (j >= cols) return;
  float v = W[(size_t)k * cols + j];
  ushort_t hi = f2bf(v);
  float rem = v - bf2f(hi);
  Wthi[(size_t)l * 16384 + j * 128 + k] = hi;
  Wtlo[(size_t)l * 16384 + j * 128 + k] = f2bf(rem);
}

// ---------------- split fp32 -> bf16 hi/lo (layer-0 input) ----------------

__global__ __launch_bounds__(256) void k_split(const float* __restrict__ in,
                                               uint* __restrict__ hi2, uint* __restrict__ lo2,
                                               int n4) {
  int i = blockIdx.x * 256 + threadIdx.x;
  if (i >= n4) return;
  float4 v = ((const float4*)in)[i];
  ushort_t hx = f2bf(v.x), hy = f2bf(v.y), hz = f2bf(v.z), hw = f2bf(v.w);
  uint2 h = make_uint2((uint)hx | ((uint)hy << 16), (uint)hz | ((uint)hw << 16));
  uint2 l = make_uint2(pack2(v.x - bf2f(hx), v.y - bf2f(hy)),
                       pack2(v.z - bf2f(hz), v.w - bf2f(hw)));
  ((uint2*)hi2)[i] = h;
  ((uint2*)lo2)[i] = l;
}

// ---------------- MFMA GEMM (unchanged from round 6) ----------------

template <int COLS, int H>
__global__ __launch_bounds__(256) void k_mm(const ushort_t* __restrict__ Ahi,
                                            const ushort_t* __restrict__ Alo,
                                            const ushort_t* __restrict__ Wthi,
                                            const ushort_t* __restrict__ Wtlo,
                                            const float* __restrict__ aS,
                                            const float* __restrict__ aD,
                                            ushort_t* __restrict__ hbf,
                                            float* __restrict__ asg,
                                            float* __restrict__ adg, int N) {
  constexpr int NB = COLS / 16;
  __shared__ __align__(16) ushort_t sWhi[COLS * 136];
  __shared__ __align__(16) ushort_t sWlo[COLS * 136];
  int tid = threadIdx.x;
  int lane = tid & 63, wv = tid >> 6;
  int lj = lane & 15, lg = lane >> 4;
  int r0 = blockIdx.x * 64 + wv * 16;

  for (int idx = tid; idx < COLS * 16; idx += 256) {
    int j = idx >> 4, seg = idx & 15;
    uint4 vh = *(const uint4*)(Wthi + (size_t)j * 128 + seg * 8);
    uint4 vl = *(const uint4*)(Wtlo + (size_t)j * 128 + seg * 8);
    *(uint4*)&sWhi[j * 136 + seg * 8] = vh;
    *(uint4*)&sWlo[j * 136 + seg * 8] = vl;
  }
  __syncthreads();

  f32x4_t acc[NB];
#pragma unroll
  for (int cb = 0; cb < NB; ++cb) acc[cb] = (f32x4_t){0.f, 0.f, 0.f, 0.f};

  int rowc = r0 + lj; if (rowc >= N) rowc = N - 1;
  const ushort_t* apH = Ahi + (size_t)rowc * 128 + lg * 8;
  const ushort_t* apL = Alo + (size_t)rowc * 128 + lg * 8;

#pragma unroll
  for (int kc = 0; kc < 4; ++kc) {
    bf16x8_t ah = *(const bf16x8_t*)(apH + kc * 32);
    bf16x8_t al = *(const bf16x8_t*)(apL + kc * 32);
#pragma unroll
    for (int cb = 0; cb < NB; ++cb) {
      int boff = (cb * 16 + lj) * 136 + kc * 32 + lg * 8;
      bf16x8_t bh = *(const bf16x8_t*)&sWhi[boff];
      bf16x8_t bl = *(const bf16x8_t*)&sWlo[boff];
      acc[cb] = __builtin_amdgcn_mfma_f32_16x16x32_bf16(ah, bh, acc[cb], 0, 0, 0);
      acc[cb] = __builtin_amdgcn_mfma_f32_16x16x32_bf16(al, bh, acc[cb], 0, 0, 0);
      acc[cb] = __builtin_amdgcn_mfma_f32_16x16x32_bf16(ah, bl, acc[cb], 0, 0, 0);
    }
  }

  float asv[NB], adv[NB];
#pragma unroll
  for (int cb = 0; cb < NB; ++cb) {
    asv[cb] = aS[cb * 16 + lj];
    adv[cb] = aD[cb * 16 + lj];
  }
#pragma unroll
  for (int reg = 0; reg < 4; ++reg) {
    int row = r0 + lg * 4 + reg;
    if (H == 4) {
      float ps[4] = {0.f, 0.f, 0.f, 0.f}, pd[4] = {0.f, 0.f, 0.f, 0.f};
#pragma unroll
      for (int cb = 0; cb < NB; ++cb) {
        int h = cb >> 1;
        ps[h] += acc[cb][reg] * asv[cb];
        pd[h] += acc[cb][reg] * adv[cb];
      }
#pragma unroll
      for (int m = 1; m < 16; m <<= 1) {
#pragma unroll
        for (int h = 0; h < 4; ++h) {
          ps[h] += __shfl_xor(ps[h], m);
          pd[h] += __shfl_xor(pd[h], m);
        }
      }
      if (lj == 0 && row < N) {
        *(float4*)(asg + (size_t)row * 4) = make_float4(ps[0], ps[1], ps[2], ps[3]);
        *(float4*)(adg + (size_t)row * 4) = make_float4(pd[0], pd[1], pd[2], pd[3]);
      }
    } else {
      float ps = 0.f, pd = 0.f;
#pragma unroll
      for (int cb = 0; cb < NB; ++cb) {
        ps += acc[cb][reg] * asv[cb];
        pd += acc[cb][reg] * adv[cb];
      }
#pragma unroll
      for (int m = 1; m < 16; m <<= 1) {
        ps += __shfl_xor(ps, m);
        pd += __shfl_xor(pd, m);
      }
      if (lj == 0 && row < N) { asg[row] = ps; adg[row] = pd; }
    }
  }

  __syncthreads();
  ushort_t* bnc = sWhi + wv * (16 * 136);
#pragma unroll
  for (int cb = 0; cb < NB; ++cb)
#pragma unroll
    for (int reg = 0; reg < 4; ++reg)
      bnc[(lg * 4 + reg) * 136 + cb * 16 + lj] = f2bf(acc[cb][reg]);
  constexpr int UPR = COLS / 8;
  constexpr int NPASS = 16 * UPR / 64;
#pragma unroll
  for (int p = 0; p < NPASS; ++p) {
    int u = p * 64 + lane;
    int rl = u / UPR, sg = u % UPR;
    if (r0 + rl < N)
      *(uint4*)(hbf + (size_t)(r0 + rl) * COLS + sg * 8) = *(const uint4*)&bnc[rl * 136 + sg * 8];
  }
}

// ---------------- aggregation: one wave per destination node ----------------
// 16B/lane gather: wave split into EPI groups of LPE lanes; group `sub`
// handles edge i+sub, lane covers 8 fixed channels. Cross-group shfl reduce
// at the end. No-max softmax.
// MODE 0: fp32 out. MODE 1: packed-bf16 out + (hi,lo) split for next GEMM.

template <int H, int C, int MODE>
__global__ __launch_bounds__(256) void k_agg(const int* __restrict__ rp, const int* __restrict__ col,
                                             const ushort_t* __restrict__ hbf,
                                             const float* __restrict__ asg,
                                             const float* __restrict__ adg,
                                             const float* __restrict__ bias,
                                             float* __restrict__ out,
                                             uint* __restrict__ outp,
                                             uint* __restrict__ ohi, uint* __restrict__ olo,
                                             int N) {
  constexpr int HC = H * C;                 // 128 or 64
  constexpr int LPE = HC / 8;               // lanes per edge: 16 (H=4) / 8 (H=1)
  constexpr int EPI = 64 / LPE;             // edges per iter: 4 / 8
  __shared__ float shp[4][64 * H];
  int lane = threadIdx.x & 63;
  int wv = threadIdx.x >> 6;
  int n = blockIdx.x * 4 + wv;
  if (n >= N) return;

  int sub = lane / LPE;                     // edge group
  int le = lane % LPE;                      // lane within edge
  int ch0 = le * 8;                         // first of 8 channels
  int head = (H == 4) ? (ch0 >> 5) : 0;

  float d0 = 0.f, d1 = 0.f, d2 = 0.f, d3 = 0.f;
  if (H == 4) {
    float4 t = *(const float4*)(adg + (size_t)n * 4);
    d0 = t.x; d1 = t.y; d2 = t.z; d3 = t.w;
  } else {
    d0 = adg[n];
  }

  int s0 = rp[n], s1 = rp[n + 1];
  float denom = 0.f;
  float a[8];
#pragma unroll
  for (int k = 0; k < 8; ++k) a[k] = 0.f;

  for (int base = s0; base < s1; base += 64) {
    int lim = s1 - base; if (lim > 64) lim = 64;
    int j = base + lane;
    bool valid = j < s1;
    int cj = valid ? col[j] : 0;

    // per-lane p for all heads of this lane's own edge -> LDS
    if (H == 4) {
      float4 t = *(const float4*)(asg + (size_t)cj * 4);
      float4 p;
      p.x = valid ? __expf(leaky(t.x + d0)) : 0.f;
      p.y = valid ? __expf(leaky(t.y + d1)) : 0.f;
      p.z = valid ? __expf(leaky(t.z + d2)) : 0.f;
      p.w = valid ? __expf(leaky(t.w + d3)) : 0.f;
      *(float4*)&shp[wv][lane * 4] = p;
    } else {
      float t = asg[cj];
      shp[wv][lane] = valid ? __expf(leaky(t + d0)) : 0.f;
    }
    __builtin_amdgcn_sched_barrier(0);

    // EPI edges per iteration; tail groups read p=0 from LDS (safe)
    for (int i = 0; i < lim; i += EPI) {
      int e = i + sub;                              // < 64 always
      int s = __shfl(cj, e);
      float p = (H == 4) ? shp[wv][e * 4 + head] : shp[wv][e];
      uint4 hv = *(const uint4*)(hbf + (size_t)s * HC + ch0);
      a[0] += p * bflo(hv.x); a[1] += p * bfhi(hv.x);
      a[2] += p * bflo(hv.y); a[3] += p * bfhi(hv.y);
      a[4] += p * bflo(hv.z); a[5] += p * bfhi(hv.z);
      a[6] += p * bflo(hv.w); a[7] += p * bfhi(hv.w);
      denom += p;
    }
  }

  // cross-group reduce (combine the EPI edge-subsets; le stays fixed)
#pragma unroll
  for (int m = LPE; m < 64; m <<= 1) {
#pragma unroll
    for (int k = 0; k < 8; ++k) a[k] += __shfl_xor(a[k], m);
    denom += __shfl_xor(denom, m);
  }

  if (sub != 0) return;
  float inv = 1.f / denom;
  float o[8];
#pragma unroll
  for (int k = 0; k < 8; ++k) o[k] = a[k] * inv + bias[ch0 + k];

  if (MODE == 0) {
    float4 w0 = make_float4(o[0], o[1], o[2], o[3]);
    float4 w1 = make_float4(o[4], o[5], o[6], o[7]);
    *(float4*)(out + (size_t)n * HC + ch0) = w0;
    *(float4*)(out + (size_t)n * HC + ch0 + 4) = w1;
  } else {
    uint hw[4], lw[4];
#pragma unroll
    for (int k = 0; k < 4; ++k) {
      ushort_t hx = f2bf(o[2 * k]), hy = f2bf(o[2 * k + 1]);
      hw[k] = (uint)hx | ((uint)hy << 16);
      lw[k] = pack2(o[2 * k] - bf2f(hx), o[2 * k + 1] - bf2f(hy));
    }
    uint4 hv = make_uint4(hw[0], hw[1], hw[2], hw[3]);
    uint4 lv = make_uint4(lw[0], lw[1], lw[2], lw[3]);
    *(uint4*)(outp + (size_t)n * 64 + le * 4) = hv;   // skip (bf16)
    *(uint4*)(ohi + (size_t)n * 64 + le * 4) = hv;    // next-GEMM hi
    *(uint4*)(olo + (size_t)n * 64 + le * 4) = lv;    // next-GEMM lo
  }
}

// ---------------- BatchNorm (training-mode batch stats) ----------------

__global__ __launch_bounds__(512) void k_bnstats1(const float* __restrict__ t,
                                                  float* __restrict__ p1, float* __restrict__ p2,
                                                  int N) {
  __shared__ float ls[4][128], ls2[4][128];
  int c = threadIdx.x & 127, q = threadIdx.x >> 7;
  float s = 0.f, s2 = 0.f;
  for (int r = blockIdx.x * 4 + q; r < N; r += gridDim.x * 4) {
    float v = t[(size_t)r * 128 + c];
    s += v;
    s2 += v * v;
  }
  ls[q][c] = s; ls2[q][c] = s2;
  __syncthreads();
  if (q == 0) {
    s = ls[0][c] + ls[1][c] + ls[2][c] + ls[3][c];
    s2 = ls2[0][c] + ls2[1][c] + ls2[2][c] + ls2[3][c];
    p1[blockIdx.x * 128 + c] = s;
    p2[blockIdx.x * 128 + c] = s2;
  }
}

__global__ void k_bnstats2(const float* __restrict__ p1, const float* __restrict__ p2,
                           float* __restrict__ mu, float* __restrict__ rstd, int G, int N) {
  int c = threadIdx.x;
  float s = 0.f, s2 = 0.f;
  for (int b = 0; b < G; ++b) { s += p1[b * 128 + c]; s2 += p2[b * 128 + c]; }
  float m = s / (float)N;
  float var = s2 / (float)N - m * m;
  mu[c] = m;
  rstd[c] = rsqrtf(var + 1e-5f);
}

// out1 = relu(bn(t)); writes out1 as packed bf16 + (hi,lo) split (next GEMM's A)
__global__ __launch_bounds__(256) void k_bnapply1(const float* __restrict__ t,
                                                  const float* __restrict__ mu,
                                                  const float* __restrict__ rstd,
                                                  const float* __restrict__ g,
                                                  const float* __restrict__ be,
                                                  uint* __restrict__ o1p,
                                                  uint* __restrict__ ohi, uint* __restrict__ olo,
                                                  int n4) {
  int i = blockIdx.x * 256 + threadIdx.x;
  if (i >= n4) return;
  float4 v = ((const float4*)t)[i];
  int c = (i & 31) * 4;
  float4 r;
  r.x = fmaxf((v.x - mu[c + 0]) * rstd[c + 0] * g[c + 0] + be[c + 0], 0.f);
  r.y = fmaxf((v.y - mu[c + 1]) * rstd[c + 1] * g[c + 1] + be[c + 1], 0.f);
  r.z = fmaxf((v.z - mu[c + 2]) * rstd[c + 2] * g[c + 2] + be[c + 2], 0.f);
  r.w = fmaxf((v.w - mu[c + 3]) * rstd[c + 3] * g[c + 3] + be[c + 3], 0.f);
  ushort_t hx = f2bf(r.x), hy = f2bf(r.y), hz = f2bf(r.z), hw = f2bf(r.w);
  uint2 h = make_uint2((uint)hx | ((uint)hy << 16), (uint)hz | ((uint)hw << 16));
  ((uint2*)o1p)[i] = h;
  ((uint2*)ohi)[i] = h;
  ((uint2*)olo)[i] = make_uint2(pack2(r.x - bf2f(hx), r.y - bf2f(hy)),
                                pack2(r.z - bf2f(hz), r.w - bf2f(hw)));
}

// out2 = relu(bn(t) + 0.5*skip); sum = out1 + out2 -> (hi,lo) split only
__global__ __launch_bounds__(256) void k_bnapply2(const float* __restrict__ t,
                                                  const uint* __restrict__ skp,
                                                  const uint* __restrict__ o1p,
                                                  const float* __restrict__ mu,
                                                  const float* __restrict__ rstd,
                                                  const float* __restrict__ g,
                                                  const float* __restrict__ be,
                                                  uint* __restrict__ ohi, uint* __restrict__ olo,
                                                  int n4) {
  int i = blockIdx.x * 256 + threadIdx.x;
  if (i >= n4) return;
  float4 v = ((const float4*)t)[i];
  uint2 sku = ((const uint2*)skp)[i];
  uint2 o1u = ((const uint2*)o1p)[i];
  int c = (i & 31) * 4;
  float4 r;
  r.x = bflo(o1u.x) + fmaxf((v.x - mu[c + 0]) * rstd[c + 0] * g[c + 0] + be[c + 0] + 0.5f * bflo(sku.x), 0.f);
  r.y = bfhi(o1u.x) + fmaxf((v.y - mu[c + 1]) * rstd[c + 1] * g[c + 1] + be[c + 1] + 0.5f * bfhi(sku.x), 0.f);
  r.z = bflo(o1u.y) + fmaxf((v.z - mu[c + 2]) * rstd[c + 2] * g[c + 2] + be[c + 2] + 0.5f * bflo(sku.y), 0.f);
  r.w = bfhi(o1u.y) + fmaxf((v.w - mu[c + 3]) * rstd[c + 3] * g[c + 3] + be[c + 3] + 0.5f * bfhi(sku.y), 0.f);
  ushort_t hx = f2bf(r.x), hy = f2bf(r.y), hz = f2bf(r.z), hw = f2bf(r.w);
  ((uint2*)ohi)[i] = make_uint2((uint)hx | ((uint)hy << 16), (uint)hz | ((uint)hw << 16));
  ((uint2*)olo)[i] = make_uint2(pack2(r.x - bf2f(hx), r.y - bf2f(hy)),
                                pack2(r.z - bf2f(hz), r.w - bf2f(hw)));
}

// ---------------------------------------------------------------------------

extern "C" void kernel_launch(void* const* d_in, const int* in_sizes, int n_in,
                              void* d_out, int out_size, void* d_ws, size_t ws_size,
                              hipStream_t stream) {
  const float* x = (const float*)d_in[0];
  const int* ei = (const int*)d_in[1];
  const float* W[4]  = {(const float*)d_in[2], (const float*)d_in[6],
                        (const float*)d_in[10], (const float*)d_in[14]};
  const float* AS[4] = {(const float*)d_in[3], (const float*)d_in[7],
                        (const float*)d_in[11], (const float*)d_in[15]};
  const float* AD[4] = {(const float*)d_in[4], (const float*)d_in[8],
                        (const float*)d_in[12], (const float*)d_in[16]};
  const float* B[4]  = {(const float*)d_in[5], (const float*)d_in[9],
                        (const float*)d_in[13], (const float*)d_in[17]};
  const float* g1 = (const float*)d_in[18];
  const float* be1 = (const float*)d_in[19];
  const float* g2 = (const float*)d_in[20];
  const float* be2 = (const float*)d_in[21];

  const int N = in_sizes[0] / 128;
  const int ER = in_sizes[1] / 2;
  const int ET = ER + N;

  char* ws = (char*)d_ws;
  size_t off = 0;
  auto carve = [&](size_t bytes) {
    size_t o = off;
    off = (off + bytes + 255) & ~(size_t)255;
    return (void*)(ws + o);
  };
  int* rowptr     = (int*)carve((size_t)(N + 1) * 4);
  int* col        = (int*)carve((size_t)ET * 4);
  int* bsums      = (int*)carve(64 * 4);
  float* asg      = (float*)carve((size_t)N * 4 * 4);
  float* adg      = (float*)carve((size_t)N * 4 * 4);
  ushort_t* hbf   = (ushort_t*)carve((size_t)N * 128 * 2);
  ushort_t* ahi   = (ushort_t*)carve((size_t)N * 128 * 2);
  ushort_t* alo   = (ushort_t*)carve((size_t)N * 128 * 2);
  uint* skipb     = (uint*)carve((size_t)N * 64 * 4);     // packed bf16 [N,128]
  uint* out1b     = (uint*)carve((size_t)N * 64 * 4);     // packed bf16 [N,128]
  float* tbuf     = (float*)carve((size_t)N * 128 * 4);
  ushort_t* Wthi  = (ushort_t*)carve(4 * 16384 * 2);
  ushort_t* Wtlo  = (ushort_t*)carve(4 * 16384 * 2);
  float* p1       = (float*)carve(128 * 128 * 4);
  float* p2       = (float*)carve(128 * 128 * 4);
  float* mu       = (float*)carve(128 * 4);
  float* rstd     = (float*)carve(128 * 4);
  int* fill       = (int*)asg;   // alias: fill dead before asg first written
  (void)ws_size;

  const int nb = (N + 2047) / 2048;
  const int gE = (ET + 255) / 256;
  const int gN4 = (N + 3) / 4;
  const int gM = (N + 63) / 64;
  const int n4 = N * 32;
  const int gP = (n4 + 255) / 256;

  // ---- CSR build + weight prep + input split ----
  hipMemsetAsync(fill, 0, (size_t)N * 4, stream);
  k_deg<<<gE, 256, 0, stream>>>(ei, ER, ET, fill);
  k_scan1<<<nb, 256, 0, stream>>>(fill, rowptr, bsums, N);
  k_scan2<<<1, 1, 0, stream>>>(bsums, nb);
  k_scan3<<<(N + 256) / 256, 256, 0, stream>>>(rowptr, bsums, N, ET);
  hipMemsetAsync(fill, 0, (size_t)N * 4, stream);
  k_scatter<<<gE, 256, 0, stream>>>(ei, ER, ET, rowptr, fill, col);
  k_prepW<<<256, 256, 0, stream>>>(W[0], W[1], W[2], W[3], Wthi, Wtlo);
  k_split<<<gP, 256, 0, stream>>>(x, (uint*)ahi, (uint*)alo, n4);

  // ---- layer 0: x -> skipb(bf16) + hi/lo for layer-1 GEMM ----
  k_mm<128, 4><<<gM, 256, 0, stream>>>(ahi, alo, Wthi, Wtlo, AS[0], AD[0], hbf, asg, adg, N);
  k_agg<4, 32, 1><<<gN4, 256, 0, stream>>>(rowptr, col, hbf, asg, adg, B[0], nullptr,
                                           skipb, (uint*)ahi, (uint*)alo, N);

  // ---- layer 1 ----
  k_mm<128, 4><<<gM, 256, 0, stream>>>(ahi, alo, Wthi + 16384, Wtlo + 16384, AS[1], AD[1],
                                       hbf, asg, adg, N);
  k_agg<4, 32, 0><<<gN4, 256, 0, stream>>>(rowptr, col, hbf, asg, adg, B[1], tbuf,
                                           nullptr, nullptr, nullptr, N);
  k_bnstats1<<<128, 512, 0, stream>>>(tbuf, p1, p2, N);
  k_bnstats2<<<1, 128, 0, stream>>>(p1, p2, mu, rstd, 128, N);
  k_bnapply1<<<gP, 256, 0, stream>>>(tbuf, mu, rstd, g1, be1, out1b, (uint*)ahi, (uint*)alo, n4);

  // ---- layer 2 ----
  k_mm<128, 4><<<gM, 256, 0, stream>>>(ahi, alo, Wthi + 2 * 16384, Wtlo + 2 * 16384, AS[2], AD[2],
                                       hbf, asg, adg, N);
  k_agg<4, 32, 0><<<gN4, 256, 0, stream>>>(rowptr, col, hbf, asg, adg, B[2], tbuf,
                                           nullptr, nullptr, nullptr, N);
  k_bnstats1<<<128, 512, 0, stream>>>(tbuf, p1, p2, N);
  k_bnstats2<<<1, 128, 0, stream>>>(p1, p2, mu, rstd, 128, N);
  k_bnapply2<<<gP, 256, 0, stream>>>(tbuf, skipb, out1b, mu, rstd, g2, be2,
                                     (uint*)ahi, (uint*)alo, n4);

  // ---- layer 3: -> d_out (H=1, C=64) ----
  k_mm<64, 1><<<gM, 256, 0, stream>>>(ahi, alo, Wthi + 3 * 16384, Wtlo + 3 * 16384, AS[3], AD[3],
                                      hbf, asg, adg, N);
  k_agg<1, 64, 0><<<gN4, 256, 0, stream>>>(rowptr, col, hbf, asg, adg, B[3], (float*)d_out,
                                           nullptr, nullptr, nullptr, N);
}

// Round 11
// 915.670 us; speedup vs baseline: 1.9544x; 1.0006x over previous
//
#include <hip/hip_runtime.h>
#include <cstdint>
#include <cstddef>

// ---------------------------------------------------------------------------
// GAT 4-layer network.
// k_mm: MFMA GEMM (split-bf16 x3 == fp32) with alpha dots folded in as extra
//       GEMM columns (alpha = x @ (W a), precomputed in k_prepW). Layer 0
//       reads fp32 x directly (in-register hi/lo split; k_split eliminated).
// k_agg: CSR segment softmax, no-max, wide 16B/lane gather (4 edges/iter).
// CSR built per launch. skip/out1 carried as packed bf16.
// ---------------------------------------------------------------------------

typedef unsigned int uint;
typedef unsigned short ushort_t;
typedef __attribute__((ext_vector_type(8))) short bf16x8_t;   // 8 bf16 = 4 VGPR
typedef __attribute__((ext_vector_type(4))) float f32x4_t;

__device__ __forceinline__ float leaky(float e) { return e < 0.f ? 0.2f * e : e; }
__device__ __forceinline__ float bflo(uint u) { return __uint_as_float(u << 16); }
__device__ __forceinline__ float bfhi(uint u) { return __uint_as_float(u & 0xffff0000u); }
__device__ __forceinline__ ushort_t f2bf(float f) {
  uint u = __float_as_uint(f);
  u += 0x7fffu + ((u >> 16) & 1u);           // round-to-nearest-even
  return (ushort_t)(u >> 16);
}
__device__ __forceinline__ float bf2f(ushort_t h) { return __uint_as_float((uint)h << 16); }
__device__ __forceinline__ uint pack2(float a, float b) {
  return (uint)f2bf(a) | ((uint)f2bf(b) << 16);
}

// ---------------- CSR build ----------------

__global__ __launch_bounds__(256) void k_deg(const int* __restrict__ ei, int ER, int ET,
                                             int* __restrict__ deg) {
  int e = blockIdx.x * 256 + threadIdx.x;
  if (e >= ET) return;
  int d = (e < ER) ? ei[ER + e] : (e - ER);
  atomicAdd(&deg[d], 1);
}

__global__ __launch_bounds__(256) void k_scan1(const int* __restrict__ deg, int* __restrict__ rp,
                                               int* __restrict__ bsums, int n) {
  __shared__ int sh[256];
  int tid = threadIdx.x;
  int base = blockIdx.x * 2048 + tid * 8;
  int pre[8];
  int s = 0;
#pragma unroll
  for (int j = 0; j < 8; ++j) {
    int idx = base + j;
    int v = (idx < n) ? deg[idx] : 0;
    pre[j] = s;
    s += v;
  }
  sh[tid] = s;
  __syncthreads();
  for (int d = 1; d < 256; d <<= 1) {
    int t = (tid >= d) ? sh[tid - d] : 0;
    __syncthreads();
    if (tid >= d) sh[tid] += t;
    __syncthreads();
  }
  int excl = sh[tid] - s;
#pragma unroll
  for (int j = 0; j < 8; ++j) {
    int idx = base + j;
    if (idx < n) rp[idx] = excl + pre[j];
  }
  if (tid == 255) bsums[blockIdx.x] = sh[255];
}

__global__ void k_scan2(int* bsums, int nb) {
  for (int i = 1; i < nb; ++i) bsums[i] += bsums[i - 1];
}

__global__ __launch_bounds__(256) void k_scan3(int* __restrict__ rp, const int* __restrict__ bsums,
                                               int n, int ET) {
  int i = blockIdx.x * 256 + threadIdx.x;
  if (i > n) return;
  if (i == n) { rp[n] = ET; return; }
  int b = i >> 11;
  if (b > 0) rp[i] += bsums[b - 1];
}

__global__ __launch_bounds__(256) void k_scatter(const int* __restrict__ ei, int ER, int ET,
                                                 const int* __restrict__ rp, int* __restrict__ fill,
                                                 int* __restrict__ col) {
  int e = blockIdx.x * 256 + threadIdx.x;
  if (e >= ET) return;
  int s, d;
  if (e < ER) { s = ei[e]; d = ei[ER + e]; } else { s = e - ER; d = s; }
  int pos = rp[d] + atomicAdd(&fill[d], 1);
  col[pos] = s;
}

// ---------------- weight prep: W^T (+ alpha columns) split into bf16 hi/lo --
// Layout per layer l: base l*144*128, rows j (pitch 128 over k):
//   j <  cols          : W^T[j][k]
//   cols   <= j < +H   : Wa_src[k, h=j-cols]     (alpha_src = x . (W a_src))
//   +H     <= j < +2H  : Wa_dst[k, h=j-cols-H]
//   else               : 0
// H=4: cols=128, alpha rows 128..135, zeros to 143. H=1: cols=64, rows 64,65.

__global__ __launch_bounds__(256) void k_prepW(const float* __restrict__ W0,
                                               const float* __restrict__ W1,
                                               const float* __restrict__ W2,
                                               const float* __restrict__ W3,
                                               const float* __restrict__ AS0,
                                               const float* __restrict__ AS1,
                                               const float* __restrict__ AS2,
                                               const float* __restrict__ AS3,
                                               const float* __restrict__ AD0,
                                               const float* __restrict__ AD1,
                                               const float* __restrict__ AD2,
                                               const float* __restrict__ AD3,
                                               ushort_t* __restrict__ Wthi,
                                               ushort_t* __restrict__ Wtlo) {
  int id = blockIdx.x * 256 + threadIdx.x;
  if (id >= 4 * 144 * 128) return;
  int l = id / (144 * 128);
  int t = id % (144 * 128);
  int j = t >> 7, k = t & 127;
  const float* W  = (l == 0) ? W0  : (l == 1) ? W1  : (l == 2) ? W2  : W3;
  const float* aS = (l == 0) ? AS0 : (l == 1) ? AS1 : (l == 2) ? AS2 : AS3;
  const float* aD = (l == 0) ? AD0 : (l == 1) ? AD1 : (l == 2) ? AD2 : AD3;
  int cols = (l == 3) ? 64 : 128;
  int H = (l == 3) ? 1 : 4;
  int C = (l == 3) ? 64 : 32;
  float v = 0.f;
  if (j < cols) {
    v = W[(size_t)k * cols + j];
  } else if (j < cols + H) {
    int h = j - cols;
    for (int c = 0; c < C; ++c) v += W[(size_t)k * cols + h * C + c] * aS[h * C + c];
  } else if (j < cols + 2 * H) {
    int h = j - cols - H;
    for (int c = 0; c < C; ++c) v += W[(size_t)k * cols + h * C + c] * aD[h * C + c];
  }
  ushort_t hi = f2bf(v);
  float rem = v - bf2f(hi);
  Wthi[(size_t)l * 144 * 128 + j * 128 + k] = hi;
  Wtlo[(size_t)l * 144 * 128 + j * 128 + k] = f2bf(rem);
}

// ---------------- MFMA GEMM: h_bf16[N,COLS] = A[N,128] @ W[128,COLS]
// + alpha columns (cb = COLS/16). Wave = 16 rows; block = 4 waves = 64 rows.
// SRC=1: A from fp32 Xf (in-register hi/lo split). SRC=0: A from (Ahi,Alo).
// v_mfma_f32_16x16x32_bf16: A row=lane&15, k=(lane>>4)*8+e;
//                           B col=lane&15 same k; C/D col=lane&15, row=(lane>>4)*4+reg.

template <int COLS, int CP, int H, int SRC>
__global__ __launch_bounds__(256) void k_mm(const float* __restrict__ Xf,
                                            const ushort_t* __restrict__ Ahi,
                                            const ushort_t* __restrict__ Alo,
                                            const ushort_t* __restrict__ Wthi,
                                            const ushort_t* __restrict__ Wtlo,
                                            ushort_t* __restrict__ hbf,
                                            float* __restrict__ asg,
                                            float* __restrict__ adg, int N) {
  constexpr int NB = CP / 16;               // MFMA col-blocks incl. alpha block
  constexpr int NBH = COLS / 16;            // real h col-blocks
  __shared__ __align__(16) ushort_t sWhi[CP * 136];
  __shared__ __align__(16) ushort_t sWlo[CP * 136];
  int tid = threadIdx.x;
  int lane = tid & 63, wv = tid >> 6;
  int lj = lane & 15, lg = lane >> 4;
  int r0 = blockIdx.x * 64 + wv * 16;

  // stage W^T hi/lo into padded LDS (row pitch 136 elems)
  for (int idx = tid; idx < CP * 16; idx += 256) {
    int j = idx >> 4, seg = idx & 15;
    uint4 vh = *(const uint4*)(Wthi + (size_t)j * 128 + seg * 8);
    uint4 vl = *(const uint4*)(Wtlo + (size_t)j * 128 + seg * 8);
    *(uint4*)&sWhi[j * 136 + seg * 8] = vh;
    *(uint4*)&sWlo[j * 136 + seg * 8] = vl;
  }
  __syncthreads();

  f32x4_t acc[NB];
#pragma unroll
  for (int cb = 0; cb < NB; ++cb) acc[cb] = (f32x4_t){0.f, 0.f, 0.f, 0.f};

  int rowc = r0 + lj; if (rowc >= N) rowc = N - 1;

#pragma unroll
  for (int kc = 0; kc < 4; ++kc) {
    bf16x8_t ah, al;
    if (SRC == 1) {
      // fp32 source, split in-register
      const float* xp = Xf + (size_t)rowc * 128 + kc * 32 + lg * 8;
      float xv[8];
      *(float4*)&xv[0] = *(const float4*)xp;
      *(float4*)&xv[4] = *(const float4*)(xp + 4);
#pragma unroll
      for (int e = 0; e < 8; ++e) {
        ushort_t hi = f2bf(xv[e]);
        ah[e] = (short)hi;
        al[e] = (short)f2bf(xv[e] - bf2f(hi));
      }
    } else {
      ah = *(const bf16x8_t*)(Ahi + (size_t)rowc * 128 + kc * 32 + lg * 8);
      al = *(const bf16x8_t*)(Alo + (size_t)rowc * 128 + kc * 32 + lg * 8);
    }
#pragma unroll
    for (int cb = 0; cb < NB; ++cb) {
      int boff = (cb * 16 + lj) * 136 + kc * 32 + lg * 8;
      bf16x8_t bh = *(const bf16x8_t*)&sWhi[boff];
      bf16x8_t bl = *(const bf16x8_t*)&sWlo[boff];
      acc[cb] = __builtin_amdgcn_mfma_f32_16x16x32_bf16(ah, bh, acc[cb], 0, 0, 0);
      acc[cb] = __builtin_amdgcn_mfma_f32_16x16x32_bf16(al, bh, acc[cb], 0, 0, 0);
      acc[cb] = __builtin_amdgcn_mfma_f32_16x16x32_bf16(ah, bl, acc[cb], 0, 0, 0);
    }
  }

  // ---- alpha stores: block cb=NBH holds cols COLS..COLS+2H-1 ----
#pragma unroll
  for (int reg = 0; reg < 4; ++reg) {
    int row = r0 + lg * 4 + reg;
    if (row < N) {
      float av = acc[NBH][reg];
      if (H == 4) {
        if (lj < 4) asg[(size_t)row * 4 + lj] = av;
        else if (lj < 8) adg[(size_t)row * 4 + (lj - 4)] = av;
      } else {
        if (lj == 0) asg[row] = av;
        else if (lj == 1) adg[row] = av;
      }
    }
  }

  // ---- h bf16 store via LDS bounce (reuse sWhi after barrier) ----
  __syncthreads();
  ushort_t* bnc = sWhi + wv * (16 * 136);
#pragma unroll
  for (int cb = 0; cb < NBH; ++cb)
#pragma unroll
    for (int reg = 0; reg < 4; ++reg)
      bnc[(lg * 4 + reg) * 136 + cb * 16 + lj] = f2bf(acc[cb][reg]);
  constexpr int UPR = COLS / 8;
  constexpr int NPASS = 16 * UPR / 64;
#pragma unroll
  for (int p = 0; p < NPASS; ++p) {
    int u = p * 64 + lane;
    int rl = u / UPR, sg = u % UPR;
    if (r0 + rl < N)
      *(uint4*)(hbf + (size_t)(r0 + rl) * COLS + sg * 8) = *(const uint4*)&bnc[rl * 136 + sg * 8];
  }
}

// ---------------- aggregation: one wave per destination node ----------------
// 16B/lane gather: EPI groups of LPE lanes; group `sub` handles edge i+sub,
// lane covers 8 fixed channels. Cross-group shfl reduce. No-max softmax.
// MODE 0: fp32 out. MODE 1: packed-bf16 out + (hi,lo) split for next GEMM.

template <int H, int C, int MODE>
__global__ __launch_bounds__(256) void k_agg(const int* __restrict__ rp, const int* __restrict__ col,
                                             const ushort_t* __restrict__ hbf,
                                             const float* __restrict__ asg,
                                             const float* __restrict__ adg,
                                             const float* __restrict__ bias,
                                             float* __restrict__ out,
                                             uint* __restrict__ outp,
                                             uint* __restrict__ ohi, uint* __restrict__ olo,
                                             int N) {
  constexpr int HC = H * C;                 // 128 or 64
  constexpr int LPE = HC / 8;               // lanes per edge: 16 (H=4) / 8 (H=1)
  constexpr int EPI = 64 / LPE;             // edges per iter: 4 / 8
  __shared__ float shp[4][64 * H];
  int lane = threadIdx.x & 63;
  int wv = threadIdx.x >> 6;
  int n = blockIdx.x * 4 + wv;
  if (n >= N) return;

  int sub = lane / LPE;                     // edge group
  int le = lane % LPE;                      // lane within edge
  int ch0 = le * 8;                         // first of 8 channels
  int head = (H == 4) ? (ch0 >> 5) : 0;

  float d0 = 0.f, d1 = 0.f, d2 = 0.f, d3 = 0.f;
  if (H == 4) {
    float4 t = *(const float4*)(adg + (size_t)n * 4);
    d0 = t.x; d1 = t.y; d2 = t.z; d3 = t.w;
  } else {
    d0 = adg[n];
  }

  int s0 = rp[n], s1 = rp[n + 1];
  float denom = 0.f;
  float a[8];
#pragma unroll
  for (int k = 0; k < 8; ++k) a[k] = 0.f;

  for (int base = s0; base < s1; base += 64) {
    int lim = s1 - base; if (lim > 64) lim = 64;
    int j = base + lane;
    bool valid = j < s1;
    int cj = valid ? col[j] : 0;

    if (H == 4) {
      float4 t = *(const float4*)(asg + (size_t)cj * 4);
      float4 p;
      p.x = valid ? __expf(leaky(t.x + d0)) : 0.f;
      p.y = valid ? __expf(leaky(t.y + d1)) : 0.f;
      p.z = valid ? __expf(leaky(t.z + d2)) : 0.f;
      p.w = valid ? __expf(leaky(t.w + d3)) : 0.f;
      *(float4*)&shp[wv][lane * 4] = p;
    } else {
      float t = asg[cj];
      shp[wv][lane] = valid ? __expf(leaky(t + d0)) : 0.f;
    }
    __builtin_amdgcn_sched_barrier(0);

    for (int i = 0; i < lim; i += EPI) {
      int e = i + sub;                              // < 64 always
      int s = __shfl(cj, e);
      float p = (H == 4) ? shp[wv][e * 4 + head] : shp[wv][e];
      uint4 hv = *(const uint4*)(hbf + (size_t)s * HC + ch0);
      a[0] += p * bflo(hv.x); a[1] += p * bfhi(hv.x);
      a[2] += p * bflo(hv.y); a[3] += p * bfhi(hv.y);
      a[4] += p * bflo(hv.z); a[5] += p * bfhi(hv.z);
      a[6] += p * bflo(hv.w); a[7] += p * bfhi(hv.w);
      denom += p;
    }
  }

#pragma unroll
  for (int m = LPE; m < 64; m <<= 1) {
#pragma unroll
    for (int k = 0; k < 8; ++k) a[k] += __shfl_xor(a[k], m);
    denom += __shfl_xor(denom, m);
  }

  if (sub != 0) return;
  float inv = 1.f / denom;
  float o[8];
#pragma unroll
  for (int k = 0; k < 8; ++k) o[k] = a[k] * inv + bias[ch0 + k];

  if (MODE == 0) {
    float4 w0 = make_float4(o[0], o[1], o[2], o[3]);
    float4 w1 = make_float4(o[4], o[5], o[6], o[7]);
    *(float4*)(out + (size_t)n * HC + ch0) = w0;
    *(float4*)(out + (size_t)n * HC + ch0 + 4) = w1;
  } else {
    uint hw[4], lw[4];
#pragma unroll
    for (int k = 0; k < 4; ++k) {
      ushort_t hx = f2bf(o[2 * k]), hy = f2bf(o[2 * k + 1]);
      hw[k] = (uint)hx | ((uint)hy << 16);
      lw[k] = pack2(o[2 * k] - bf2f(hx), o[2 * k + 1] - bf2f(hy));
    }
    uint4 hv = make_uint4(hw[0], hw[1], hw[2], hw[3]);
    uint4 lv = make_uint4(lw[0], lw[1], lw[2], lw[3]);
    *(uint4*)(outp + (size_t)n * 64 + le * 4) = hv;   // skip (bf16)
    *(uint4*)(ohi + (size_t)n * 64 + le * 4) = hv;    // next-GEMM hi
    *(uint4*)(olo + (size_t)n * 64 + le * 4) = lv;    // next-GEMM lo
  }
}

// ---------------- BatchNorm (training-mode batch stats) ----------------

__global__ __launch_bounds__(512) void k_bnstats1(const float* __restrict__ t,
                                                  float* __restrict__ p1, float* __restrict__ p2,
                                                  int N) {
  __shared__ float ls[4][128], ls2[4][128];
  int c = threadIdx.x & 127, q = threadIdx.x >> 7;
  float s = 0.f, s2 = 0.f;
  for (int r = blockIdx.x * 4 + q; r < N; r += gridDim.x * 4) {
    float v = t[(size_t)r * 128 + c];
    s += v;
    s2 += v * v;
  }
  ls[q][c] = s; ls2[q][c] = s2;
  __syncthreads();
  if (q == 0) {
    s = ls[0][c] + ls[1][c] + ls[2][c] + ls[3][c];
    s2 = ls2[0][c] + ls2[1][c] + ls2[2][c] + ls2[3][c];
    p1[blockIdx.x * 128 + c] = s;
    p2[blockIdx.x * 128 + c] = s2;
  }
}

__global__ void k_bnstats2(const float* __restrict__ p1, const float* __restrict__ p2,
                           float* __restrict__ mu, float* __restrict__ rstd, int G, int N) {
  int c = threadIdx.x;
  float s = 0.f, s2 = 0.f;
  for (int b = 0; b < G; ++b) { s += p1[b * 128 + c]; s2 += p2[b * 128 + c]; }
  float m = s / (float)N;
  float var = s2 / (float)N - m * m;
  mu[c] = m;
  rstd[c] = rsqrtf(var + 1e-5f);
}

// out1 = relu(bn(t)); writes out1 as packed bf16 + (hi,lo) split (next GEMM's A)
__global__ __launch_bounds__(256) void k_bnapply1(const float* __restrict__ t,
                                                  const float* __restrict__ mu,
                                                  const float* __restrict__ rstd,
                                                  const float* __restrict__ g,
                                                  const float* __restrict__ be,
                                                  uint* __restrict__ o1p,
                                                  uint* __restrict__ ohi, uint* __restrict__ olo,
                                                  int n4) {
  int i = blockIdx.x * 256 + threadIdx.x;
  if (i >= n4) return;
  float4 v = ((const float4*)t)[i];
  int c = (i & 31) * 4;
  float4 r;
  r.x = fmaxf((v.x - mu[c + 0]) * rstd[c + 0] * g[c + 0] + be[c + 0], 0.f);
  r.y = fmaxf((v.y - mu[c + 1]) * rstd[c + 1] * g[c + 1] + be[c + 1], 0.f);
  r.z = fmaxf((v.z - mu[c + 2]) * rstd[c + 2] * g[c + 2] + be[c + 2], 0.f);
  r.w = fmaxf((v.w - mu[c + 3]) * rstd[c + 3] * g[c + 3] + be[c + 3], 0.f);
  ushort_t hx = f2bf(r.x), hy = f2bf(r.y), hz = f2bf(r.z), hw = f2bf(r.w);
  uint2 h = make_uint2((uint)hx | ((uint)hy << 16), (uint)hz | ((uint)hw << 16));
  ((uint2*)o1p)[i] = h;
  ((uint2*)ohi)[i] = h;
  ((uint2*)olo)[i] = make_uint2(pack2(r.x - bf2f(hx), r.y - bf2f(hy)),
                                pack2(r.z - bf2f(hz), r.w - bf2f(hw)));
}

// out2 = relu(bn(t) + 0.5*skip); sum = out1 + out2 -> (hi,lo) split only
__global__ __launch_bounds__(256) void k_bnapply2(const float* __restrict__ t,
                                                  const uint* __restrict__ skp,
                                                  const uint* __restrict__ o1p,
                                                  const float* __restrict__ mu,
                                                  const float* __restrict__ rstd,
                                                  const float* __restrict__ g,
                                                  const float* __restrict__ be,
                                                  uint* __restrict__ ohi, uint* __restrict__ olo,
                                                  int n4) {
  int i = blockIdx.x * 256 + threadIdx.x;
  if (i >= n4) return;
  float4 v = ((const float4*)t)[i];
  uint2 sku = ((const uint2*)skp)[i];
  uint2 o1u = ((const uint2*)o1p)[i];
  int c = (i & 31) * 4;
  float4 r;
  r.x = bflo(o1u.x) + fmaxf((v.x - mu[c + 0]) * rstd[c + 0] * g[c + 0] + be[c + 0] + 0.5f * bflo(sku.x), 0.f);
  r.y = bfhi(o1u.x) + fmaxf((v.y - mu[c + 1]) * rstd[c + 1] * g[c + 1] + be[c + 1] + 0.5f * bfhi(sku.x), 0.f);
  r.z = bflo(o1u.y) + fmaxf((v.z - mu[c + 2]) * rstd[c + 2] * g[c + 2] + be[c + 2] + 0.5f * bflo(sku.y), 0.f);
  r.w = bfhi(o1u.y) + fmaxf((v.w - mu[c + 3]) * rstd[c + 3] * g[c + 3] + be[c + 3] + 0.5f * bfhi(sku.y), 0.f);
  ushort_t hx = f2bf(r.x), hy = f2bf(r.y), hz = f2bf(r.z), hw = f2bf(r.w);
  ((uint2*)ohi)[i] = make_uint2((uint)hx | ((uint)hy << 16), (uint)hz | ((uint)hw << 16));
  ((uint2*)olo)[i] = make_uint2(pack2(r.x - bf2f(hx), r.y - bf2f(hy)),
                                pack2(r.z - bf2f(hz), r.w - bf2f(hw)));
}

// ---------------------------------------------------------------------------

extern "C" void kernel_launch(void* const* d_in, const int* in_sizes, int n_in,
                              void* d_out, int out_size, void* d_ws, size_t ws_size,
                              hipStream_t stream) {
  const float* x = (const float*)d_in[0];
  const int* ei = (const int*)d_in[1];
  const float* W[4]  = {(const float*)d_in[2], (const float*)d_in[6],
                        (const float*)d_in[10], (const float*)d_in[14]};
  const float* AS[4] = {(const float*)d_in[3], (const float*)d_in[7],
                        (const float*)d_in[11], (const float*)d_in[15]};
  const float* AD[4] = {(const float*)d_in[4], (const float*)d_in[8],
                        (const float*)d_in[12], (const float*)d_in[16]};
  const float* B[4]  = {(const float*)d_in[5], (const float*)d_in[9],
                        (const float*)d_in[13], (const float*)d_in[17]};
  const float* g1 = (const float*)d_in[18];
  const float* be1 = (const float*)d_in[19];
  const float* g2 = (const float*)d_in[20];
  const float* be2 = (const float*)d_in[21];

  const int N = in_sizes[0] / 128;
  const int ER = in_sizes[1] / 2;
  const int ET = ER + N;

  char* ws = (char*)d_ws;
  size_t off = 0;
  auto carve = [&](size_t bytes) {
    size_t o = off;
    off = (off + bytes + 255) & ~(size_t)255;
    return (void*)(ws + o);
  };
  int* rowptr     = (int*)carve((size_t)(N + 1) * 4);
  int* col        = (int*)carve((size_t)ET * 4);
  int* bsums      = (int*)carve(64 * 4);
  float* asg      = (float*)carve((size_t)N * 4 * 4);
  float* adg      = (float*)carve((size_t)N * 4 * 4);
  ushort_t* hbf   = (ushort_t*)carve((size_t)N * 128 * 2);
  ushort_t* ahi   = (ushort_t*)carve((size_t)N * 128 * 2);
  ushort_t* alo   = (ushort_t*)carve((size_t)N * 128 * 2);
  uint* skipb     = (uint*)carve((size_t)N * 64 * 4);     // packed bf16 [N,128]
  uint* out1b     = (uint*)carve((size_t)N * 64 * 4);     // packed bf16 [N,128]
  float* tbuf     = (float*)carve((size_t)N * 128 * 4);
  ushort_t* Wthi  = (ushort_t*)carve(4 * 144 * 128 * 2);
  ushort_t* Wtlo  = (ushort_t*)carve(4 * 144 * 128 * 2);
  float* p1       = (float*)carve(256 * 128 * 4);
  float* p2       = (float*)carve(256 * 128 * 4);
  float* mu       = (float*)carve(128 * 4);
  float* rstd     = (float*)carve(128 * 4);
  int* fill       = (int*)asg;   // alias: fill dead before asg first written
  (void)ws_size;

  const int nb = (N + 2047) / 2048;
  const int gE = (ET + 255) / 256;
  const int gN4 = (N + 3) / 4;
  const int gM = (N + 63) / 64;
  const int n4 = N * 32;
  const int gP = (n4 + 255) / 256;
  const int gW = (4 * 144 * 128 + 255) / 256;

  // ---- CSR build + weight prep ----
  hipMemsetAsync(fill, 0, (size_t)N * 4, stream);
  k_deg<<<gE, 256, 0, stream>>>(ei, ER, ET, fill);
  k_scan1<<<nb, 256, 0, stream>>>(fill, rowptr, bsums, N);
  k_scan2<<<1, 1, 0, stream>>>(bsums, nb);
  k_scan3<<<(N + 256) / 256, 256, 0, stream>>>(rowptr, bsums, N, ET);
  hipMemsetAsync(fill, 0, (size_t)N * 4, stream);
  k_scatter<<<gE, 256, 0, stream>>>(ei, ER, ET, rowptr, fill, col);
  k_prepW<<<gW, 256, 0, stream>>>(W[0], W[1], W[2], W[3],
                                  AS[0], AS[1], AS[2], AS[3],
                                  AD[0], AD[1], AD[2], AD[3], Wthi, Wtlo);

  // ---- layer 0: fp32 x -> skipb(bf16) + hi/lo for layer-1 GEMM ----
  k_mm<128, 144, 4, 1><<<gM, 256, 0, stream>>>(x, nullptr, nullptr,
                                               Wthi, Wtlo, hbf, asg, adg, N);
  k_agg<4, 32, 1><<<gN4, 256, 0, stream>>>(rowptr, col, hbf, asg, adg, B[0], nullptr,
                                           skipb, (uint*)ahi, (uint*)alo, N);

  // ---- layer 1 ----
  k_mm<128, 144, 4, 0><<<gM, 256, 0, stream>>>(nullptr, ahi, alo,
                                               Wthi + 144 * 128, Wtlo + 144 * 128,
                                               hbf, asg, adg, N);
  k_agg<4, 32, 0><<<gN4, 256, 0, stream>>>(rowptr, col, hbf, asg, adg, B[1], tbuf,
                                           nullptr, nullptr, nullptr, N);
  k_bnstats1<<<256, 512, 0, stream>>>(tbuf, p1, p2, N);
  k_bnstats2<<<1, 128, 0, stream>>>(p1, p2, mu, rstd, 256, N);
  k_bnapply1<<<gP, 256, 0, stream>>>(tbuf, mu, rstd, g1, be1, out1b, (uint*)ahi, (uint*)alo, n4);

  // ---- layer 2 ----
  k_mm<128, 144, 4, 0><<<gM, 256, 0, stream>>>(nullptr, ahi, alo,
                                               Wthi + 2 * 144 * 128, Wtlo + 2 * 144 * 128,
                                               hbf, asg, adg, N);
  k_agg<4, 32, 0><<<gN4, 256, 0, stream>>>(rowptr, col, hbf, asg, adg, B[2], tbuf,
                                           nullptr, nullptr, nullptr, N);
  k_bnstats1<<<256, 512, 0, stream>>>(tbuf, p1, p2, N);
  k_bnstats2<<<1, 128, 0, stream>>>(p1, p2, mu, rstd, 256, N);
  k_bnapply2<<<gP, 256, 0, stream>>>(tbuf, skipb, out1b, mu, rstd, g2, be2,
                                     (uint*)ahi, (uint*)alo, n4);

  // ---- layer 3: -> d_out (H=1, C=64) ----
  k_mm<64, 80, 1, 0><<<gM, 256, 0, stream>>>(nullptr, ahi, alo,
                                             Wthi + 3 * 144 * 128, Wtlo + 3 * 144 * 128,
                                             hbf, asg, adg, N);
  k_agg<1, 64, 0><<<gN4, 256, 0, stream>>>(rowptr, col, hbf, asg, adg, B[3], (float*)d_out,
                                           nullptr, nullptr, nullptr, N);
}